// Round 1
// baseline (524.264 us; speedup 1.0000x reference)
//
#include <hip/hip_runtime.h>
#include <cstdint>
#include <cstddef>

#define NEG_SLOPE 0.2f

static __device__ __forceinline__ unsigned short f2bf(float x) {
  uint32_t u = __float_as_uint(x);
  uint32_t r = (u + 0x7FFFu + ((u >> 16) & 1u)) >> 16;
  return (unsigned short)r;
}
static __device__ __forceinline__ float bf2f(unsigned short b) {
  return __uint_as_float(((uint32_t)b) << 16);
}

// ---------------------------------------------------------------------------
// proj: ft[N,256] = feats[N,128] @ W[128,256]  (optional bf16 store)
//       el[N,8]   = sum_d ft[n,h,d] * av[h,d]
// block 256 threads; tile 64 rows x 64 cols (blockIdx.y = col quad);
// thread tile 4x4. LDS: Ws[128][64] (32KB) + Fs[64][128] rotated (32KB).
// ---------------------------------------------------------------------------
__global__ __launch_bounds__(256)
void proj_kernel(const float* __restrict__ feats, const float* __restrict__ W,
                 const float* __restrict__ av, int N,
                 unsigned short* __restrict__ ft_out, float* __restrict__ el_out) {
  __shared__ float Ws[128][64];
  __shared__ float Fs[64][128];   // Fs[r][(k + 4r) & 127] = feats[rb+r][k]
  const int t = threadIdx.x;
  const int rb = blockIdx.x * 64;
  const int cb = blockIdx.y * 64;

  // stage W cols [cb, cb+64): 128x64 floats
  for (int i = t; i < 128 * 16; i += 256) {
    int k = i >> 4, c4 = (i & 15) << 2;
    *(float4*)(&Ws[k][c4]) = *(const float4*)(&W[k * 256 + cb + c4]);
  }
  // stage feats rows [rb, rb+64) with per-row k-rotation (bank-conflict-free)
  for (int i = t; i < 64 * 32; i += 256) {
    int r = i >> 5, kc = (i & 31) << 2;
    float4 f = make_float4(0.f, 0.f, 0.f, 0.f);
    if (rb + r < N) f = *(const float4*)(&feats[(size_t)(rb + r) * 128 + kc]);
    *(float4*)(&Fs[r][(kc + 4 * r) & 127]) = f;
  }
  __syncthreads();

  const int rg = t >> 4;   // 0..15 -> rows rg*4..+4
  const int cg = t & 15;   // 0..15 -> cols cg*4..+4
  float acc[4][4] = {};

  #pragma unroll 2
  for (int k4 = 0; k4 < 128; k4 += 4) {
    float4 fv[4], wv[4];
    #pragma unroll
    for (int i = 0; i < 4; ++i) {
      int r = rg * 4 + i;
      fv[i] = *(const float4*)(&Fs[r][(k4 + 4 * r) & 127]);
    }
    #pragma unroll
    for (int kk = 0; kk < 4; ++kk)
      wv[kk] = *(const float4*)(&Ws[k4 + kk][cg * 4]);
    #pragma unroll
    for (int i = 0; i < 4; ++i) {
      const float fa[4] = {fv[i].x, fv[i].y, fv[i].z, fv[i].w};
      #pragma unroll
      for (int kk = 0; kk < 4; ++kk) {
        const float wa[4] = {wv[kk].x, wv[kk].y, wv[kk].z, wv[kk].w};
        acc[i][0] = fmaf(fa[kk], wa[0], acc[i][0]);
        acc[i][1] = fmaf(fa[kk], wa[1], acc[i][1]);
        acc[i][2] = fmaf(fa[kk], wa[2], acc[i][2]);
        acc[i][3] = fmaf(fa[kk], wa[3], acc[i][3]);
      }
    }
  }

  const int colg = cb + cg * 4;        // global col of acc[.][0]
  const int head = colg >> 5;          // global head index
  const int d0 = colg & 31;
  float av4[4];
  #pragma unroll
  for (int j = 0; j < 4; ++j) av4[j] = av[head * 32 + d0 + j];

  #pragma unroll
  for (int i = 0; i < 4; ++i) {
    int row = rb + rg * 4 + i;
    bool ok = row < N;
    float p = 0.f;
    #pragma unroll
    for (int j = 0; j < 4; ++j) p = fmaf(acc[i][j], av4[j], p);
    // reduce over the 8 lanes (cg bits 0..2) covering this head's 32 cols
    p += __shfl_xor(p, 1);
    p += __shfl_xor(p, 2);
    p += __shfl_xor(p, 4);
    if (ok) {
      if (ft_out != nullptr) {
        ushort4 u;
        u.x = f2bf(acc[i][0]); u.y = f2bf(acc[i][1]);
        u.z = f2bf(acc[i][2]); u.w = f2bf(acc[i][3]);
        *(ushort4*)(&ft_out[(size_t)row * 256 + colg]) = u;
      }
      if ((cg & 7) == 0) el_out[(size_t)row * 8 + head] = p;
    }
  }
}

// ---------------------------------------------------------------------------
__global__ void count_deg_kernel(const int* __restrict__ dst0, int E0,
                                 const int* __restrict__ dst1, int E1,
                                 int* __restrict__ deg) {
  int E = E0 + E1;
  for (int i = blockIdx.x * blockDim.x + threadIdx.x; i < E;
       i += gridDim.x * blockDim.x) {
    int d = (i < E0) ? dst0[i] : dst1[i - E0];
    atomicAdd(&deg[d], 1);
  }
}

__global__ __launch_bounds__(1024)
void scan_kernel(const int* __restrict__ deg, int* __restrict__ offs,
                 int* __restrict__ cursor, int n) {
  __shared__ int sdata[1024];
  __shared__ int s_carry;
  const int t = threadIdx.x;
  if (t == 0) s_carry = 0;
  __syncthreads();
  for (int base = 0; base < n; base += 1024) {
    int v = (base + t < n) ? deg[base + t] : 0;
    sdata[t] = v;
    __syncthreads();
    for (int off = 1; off < 1024; off <<= 1) {
      int x = (t >= off) ? sdata[t - off] : 0;
      __syncthreads();
      if (t >= off) sdata[t] += x;
      __syncthreads();
    }
    int carry = s_carry;
    if (base + t < n) {
      int excl = carry + sdata[t] - v;
      offs[base + t] = excl;
      cursor[base + t] = excl;
    }
    __syncthreads();
    if (t == 1023) s_carry = carry + sdata[1023];
    __syncthreads();
  }
  if (t == 0) offs[n] = s_carry;
}

__global__ void scatter_kernel(const int* __restrict__ src0, const int* __restrict__ dst0, int E0,
                               const int* __restrict__ src1, const int* __restrict__ dst1, int E1,
                               int* __restrict__ cursor, int* __restrict__ slots) {
  int E = E0 + E1;
  for (int i = blockIdx.x * blockDim.x + threadIdx.x; i < E;
       i += gridDim.x * blockDim.x) {
    int s, d, f;
    if (i < E0) { s = src0[i]; d = dst0[i]; f = 0; }
    else        { s = src1[i - E0]; d = dst1[i - E0]; f = 1; }
    int pos = atomicAdd(&cursor[d], 1);
    slots[pos] = s | (f << 31);
  }
}

// ---------------------------------------------------------------------------
// one wave per dst node: pass1 per-head max, pass2 exp-weighted ft gather.
// lane layout: flat = lane*4 -> h = lane>>3, d = (lane&7)*4 + j
// ---------------------------------------------------------------------------
__global__ __launch_bounds__(256)
void aggregate_kernel(const int* __restrict__ offs, const int* __restrict__ slots,
                      const float* __restrict__ el0, const float* __restrict__ el1,
                      const float* __restrict__ er,
                      const unsigned short* __restrict__ ft0,
                      const unsigned short* __restrict__ ft1,
                      float* __restrict__ rst, int Nm) {
  int gid = blockIdx.x * blockDim.x + threadIdx.x;
  int n = gid >> 6;
  int lane = threadIdx.x & 63;
  if (n >= Nm) return;
  int beg = offs[n], end = offs[n + 1];
  int h = lane >> 3;
  float o0 = 0.f, o1 = 0.f, o2 = 0.f, o3 = 0.f;
  if (beg < end) {
    float ern = er[(size_t)n * 8 + h];
    float m = -3.4e38f;
    for (int i = beg; i < end; ++i) {
      int s = slots[i];
      int srci = s & 0x7fffffff;
      const float* el = (s < 0) ? el1 : el0;
      float v = el[(size_t)srci * 8 + h] + ern;
      v = (v >= 0.f) ? v : NEG_SLOPE * v;
      m = fmaxf(m, v);
    }
    float sw = 0.f;
    for (int i = beg; i < end; ++i) {
      int s = slots[i];
      int srci = s & 0x7fffffff;
      const float* el = (s < 0) ? el1 : el0;
      const unsigned short* ft = (s < 0) ? ft1 : ft0;
      float v = el[(size_t)srci * 8 + h] + ern;
      v = (v >= 0.f) ? v : NEG_SLOPE * v;
      float w = __expf(v - m);
      sw += w;
      ushort4 f = *(const ushort4*)(&ft[(size_t)srci * 256 + lane * 4]);
      o0 = fmaf(w, bf2f(f.x), o0);
      o1 = fmaf(w, bf2f(f.y), o1);
      o2 = fmaf(w, bf2f(f.z), o2);
      o3 = fmaf(w, bf2f(f.w), o3);
    }
    float inv = 1.0f / sw;
    o0 *= inv; o1 *= inv; o2 *= inv; o3 *= inv;
  }
  *(float4*)(&rst[(size_t)n * 256 + lane * 4]) = make_float4(o0, o1, o2, o3);
}

// ---------------------------------------------------------------------------
extern "C" void kernel_launch(void* const* d_in, const int* in_sizes, int n_in,
                              void* d_out, int out_size, void* d_ws, size_t ws_size,
                              hipStream_t stream) {
  const float* master = (const float*)d_in[0];
  const float* af0    = (const float*)d_in[1];
  const float* af1    = (const float*)d_in[2];
  const int*   src0   = (const int*)d_in[3];
  const int*   dst0   = (const int*)d_in[4];
  const int*   src1   = (const int*)d_in[5];
  const int*   dst1   = (const int*)d_in[6];
  const float* Wm     = (const float*)d_in[7];
  const float* W0     = (const float*)d_in[8];
  const float* W1     = (const float*)d_in[9];
  const float* attn_l = (const float*)d_in[10];
  const float* attn_r = (const float*)d_in[11];

  const int Nm  = in_sizes[0] / 128;
  const int Na0 = in_sizes[1] / 128;
  const int Na1 = in_sizes[2] / 128;
  const int E0  = in_sizes[3];
  const int E1  = in_sizes[5];
  float* rst = (float*)d_out;

  char* ws = (char*)d_ws;
  size_t off = 0;
  auto alloc = [&](size_t b) -> char* {
    char* p = ws + off;
    off += (b + 511) & ~(size_t)511;
    return p;
  };
  unsigned short* ft0 = (unsigned short*)alloc((size_t)Na0 * 256 * sizeof(unsigned short));
  unsigned short* ft1 = (unsigned short*)alloc((size_t)Na1 * 256 * sizeof(unsigned short));
  float* el0 = (float*)alloc((size_t)Na0 * 8 * sizeof(float));
  float* el1 = (float*)alloc((size_t)Na1 * 8 * sizeof(float));
  float* er  = (float*)alloc((size_t)Nm * 8 * sizeof(float));
  int* deg    = (int*)alloc((size_t)Nm * sizeof(int));
  int* offs   = (int*)alloc((size_t)(Nm + 1) * sizeof(int));
  int* cursor = (int*)alloc((size_t)Nm * sizeof(int));
  int* slots  = (int*)alloc((size_t)(E0 + E1) * sizeof(int));

  // projections (er for master uses attn_r; el0/el1 use attn_l)
  proj_kernel<<<dim3((Nm  + 63) / 64, 4), 256, 0, stream>>>(master, Wm, attn_r, Nm,  nullptr, er);
  proj_kernel<<<dim3((Na0 + 63) / 64, 4), 256, 0, stream>>>(af0,    W0, attn_l, Na0, ft0,     el0);
  proj_kernel<<<dim3((Na1 + 63) / 64, 4), 256, 0, stream>>>(af1,    W1, attn_l, Na1, ft1,     el1);

  // CSR build over combined dst
  hipMemsetAsync(deg, 0, (size_t)Nm * sizeof(int), stream);
  count_deg_kernel<<<1024, 256, 0, stream>>>(dst0, E0, dst1, E1, deg);
  scan_kernel<<<1, 1024, 0, stream>>>(deg, offs, cursor, Nm);
  scatter_kernel<<<1024, 256, 0, stream>>>(src0, dst0, E0, src1, dst1, E1, cursor, slots);

  // per-node softmax + weighted aggregation
  aggregate_kernel<<<(Nm + 3) / 4, 256, 0, stream>>>(offs, slots, el0, el1, er,
                                                     ft0, ft1, rst, Nm);
}

// Round 2
// 501.904 us; speedup vs baseline: 1.0445x; 1.0445x over previous
//
#include <hip/hip_runtime.h>
#include <cstdint>
#include <cstddef>

#define NEG_SLOPE 0.2f

static __device__ __forceinline__ unsigned short f2bf(float x) {
  uint32_t u = __float_as_uint(x);
  uint32_t r = (u + 0x7FFFu + ((u >> 16) & 1u)) >> 16;
  return (unsigned short)r;
}
static __device__ __forceinline__ float bf2f(unsigned short b) {
  return __uint_as_float(((uint32_t)b) << 16);
}

// ---------------------------------------------------------------------------
// proj: ft[N,256] = feats[N,128] @ W[128,256]  (optional bf16 store)
//       el[N,8]   = sum_d ft[n,h,d] * av[h,d]
// block 256 threads; tile 64 rows x 64 cols (blockIdx.y = col quad);
// thread tile 4x4. LDS: Ws[128][64] (32KB) + Fs[64][128] rotated (32KB).
// ---------------------------------------------------------------------------
__global__ __launch_bounds__(256)
void proj_kernel(const float* __restrict__ feats, const float* __restrict__ W,
                 const float* __restrict__ av, int N,
                 unsigned short* __restrict__ ft_out, float* __restrict__ el_out) {
  __shared__ float Ws[128][64];
  __shared__ float Fs[64][128];   // Fs[r][(k + 4r) & 127] = feats[rb+r][k]
  const int t = threadIdx.x;
  const int rb = blockIdx.x * 64;
  const int cb = blockIdx.y * 64;

  for (int i = t; i < 128 * 16; i += 256) {
    int k = i >> 4, c4 = (i & 15) << 2;
    *(float4*)(&Ws[k][c4]) = *(const float4*)(&W[k * 256 + cb + c4]);
  }
  for (int i = t; i < 64 * 32; i += 256) {
    int r = i >> 5, kc = (i & 31) << 2;
    float4 f = make_float4(0.f, 0.f, 0.f, 0.f);
    if (rb + r < N) f = *(const float4*)(&feats[(size_t)(rb + r) * 128 + kc]);
    *(float4*)(&Fs[r][(kc + 4 * r) & 127]) = f;
  }
  __syncthreads();

  const int rg = t >> 4;
  const int cg = t & 15;
  float acc[4][4] = {};

  #pragma unroll 2
  for (int k4 = 0; k4 < 128; k4 += 4) {
    float4 fv[4], wv[4];
    #pragma unroll
    for (int i = 0; i < 4; ++i) {
      int r = rg * 4 + i;
      fv[i] = *(const float4*)(&Fs[r][(k4 + 4 * r) & 127]);
    }
    #pragma unroll
    for (int kk = 0; kk < 4; ++kk)
      wv[kk] = *(const float4*)(&Ws[k4 + kk][cg * 4]);
    #pragma unroll
    for (int i = 0; i < 4; ++i) {
      const float fa[4] = {fv[i].x, fv[i].y, fv[i].z, fv[i].w};
      #pragma unroll
      for (int kk = 0; kk < 4; ++kk) {
        const float wa[4] = {wv[kk].x, wv[kk].y, wv[kk].z, wv[kk].w};
        acc[i][0] = fmaf(fa[kk], wa[0], acc[i][0]);
        acc[i][1] = fmaf(fa[kk], wa[1], acc[i][1]);
        acc[i][2] = fmaf(fa[kk], wa[2], acc[i][2]);
        acc[i][3] = fmaf(fa[kk], wa[3], acc[i][3]);
      }
    }
  }

  const int colg = cb + cg * 4;
  const int head = colg >> 5;
  const int d0 = colg & 31;
  float av4[4];
  #pragma unroll
  for (int j = 0; j < 4; ++j) av4[j] = av[head * 32 + d0 + j];

  #pragma unroll
  for (int i = 0; i < 4; ++i) {
    int row = rb + rg * 4 + i;
    bool ok = row < N;
    float p = 0.f;
    #pragma unroll
    for (int j = 0; j < 4; ++j) p = fmaf(acc[i][j], av4[j], p);
    p += __shfl_xor(p, 1);
    p += __shfl_xor(p, 2);
    p += __shfl_xor(p, 4);
    if (ok) {
      if (ft_out != nullptr) {
        ushort4 u;
        u.x = f2bf(acc[i][0]); u.y = f2bf(acc[i][1]);
        u.z = f2bf(acc[i][2]); u.w = f2bf(acc[i][3]);
        *(ushort4*)(&ft_out[(size_t)row * 256 + colg]) = u;
      }
      if ((cg & 7) == 0) el_out[(size_t)row * 8 + head] = p;
    }
  }
}

// ---------------------------------------------------------------------------
__global__ void count_deg_kernel(const int* __restrict__ dst0, int E0,
                                 const int* __restrict__ dst1, int E1,
                                 int* __restrict__ deg) {
  int E = E0 + E1;
  for (int i = blockIdx.x * blockDim.x + threadIdx.x; i < E;
       i += gridDim.x * blockDim.x) {
    int d = (i < E0) ? dst0[i] : dst1[i - E0];
    atomicAdd(&deg[d], 1);
  }
}

// 3-phase scan: per-thread sequential chunk -> wave shfl scan -> 16-wave scan.
__global__ __launch_bounds__(1024)
void scan_kernel(const int* __restrict__ deg, int* __restrict__ offs,
                 int* __restrict__ cursor, int n) {
  __shared__ int wsum[16];
  const int t = threadIdx.x;
  const int ITEMS = (n + 1023) / 1024;
  const int base = t * ITEMS;

  int sum = 0;
  for (int i = 0; i < ITEMS; ++i) {
    int idx = base + i;
    sum += (idx < n) ? deg[idx] : 0;
  }
  // inclusive wave scan
  int v = sum;
  const int lane = t & 63, w = t >> 6;
  #pragma unroll
  for (int off = 1; off < 64; off <<= 1) {
    int x = __shfl_up(v, off);
    if (lane >= off) v += x;
  }
  if (lane == 63) wsum[w] = v;
  __syncthreads();
  if (t < 16) {
    int x = wsum[t];
    #pragma unroll
    for (int off = 1; off < 16; off <<= 1) {
      int y = __shfl_up(x, off);
      if (t >= off) x += y;
    }
    wsum[t] = x;
  }
  __syncthreads();
  int waveBase = (w > 0) ? wsum[w - 1] : 0;
  int run = waveBase + v - sum;   // exclusive prefix of this thread's chunk
  for (int i = 0; i < ITEMS; ++i) {
    int idx = base + i;
    if (idx < n) {
      offs[idx] = run;
      cursor[idx] = run;
      run += deg[idx];
    }
  }
  if (t == 1023) offs[n] = run;   // total edge count
}

__global__ void scatter_kernel(const int* __restrict__ src0, const int* __restrict__ dst0, int E0,
                               const int* __restrict__ src1, const int* __restrict__ dst1, int E1,
                               int* __restrict__ cursor, int* __restrict__ slots) {
  int E = E0 + E1;
  for (int i = blockIdx.x * blockDim.x + threadIdx.x; i < E;
       i += gridDim.x * blockDim.x) {
    int s, d, f;
    if (i < E0) { s = src0[i]; d = dst0[i]; f = 0; }
    else        { s = src1[i - E0]; d = dst1[i - E0]; f = 1; }
    int pos = atomicAdd(&cursor[d], 1);
    slots[pos] = s | (f << 31);
  }
}

// ---------------------------------------------------------------------------
// one wave per dst node, SINGLE pass: softmax without max-subtraction
// (logits = lrelu(el+er) are O(1)-bounded; exp cannot overflow; ratio is
// mathematically identical to the max-subtracted form).
// lane layout: flat = lane*4 -> h = lane>>3, d = (lane&7)*4 + j
// 1-deep software prefetch of next edge's el/ft hides part of L2/L3 latency.
// ---------------------------------------------------------------------------
__global__ __launch_bounds__(256)
void aggregate_kernel(const int* __restrict__ offs, const int* __restrict__ slots,
                      const float* __restrict__ el0, const float* __restrict__ el1,
                      const float* __restrict__ er,
                      const unsigned short* __restrict__ ft0,
                      const unsigned short* __restrict__ ft1,
                      float* __restrict__ rst, int Nm) {
  int gid = blockIdx.x * blockDim.x + threadIdx.x;
  int n = gid >> 6;
  int lane = threadIdx.x & 63;
  if (n >= Nm) return;
  int beg = offs[n], end = offs[n + 1];
  int h = lane >> 3;
  float o0 = 0.f, o1 = 0.f, o2 = 0.f, o3 = 0.f;
  if (beg < end) {
    float ern = er[(size_t)n * 8 + h];
    float sw = 0.f;

    // prologue: load edge `beg`
    int s = slots[beg];
    int srci = s & 0x7fffffff;
    float ev_c = ((s < 0) ? el1 : el0)[(size_t)srci * 8 + h];
    ushort4 f_c = *(const ushort4*)(&((s < 0) ? ft1 : ft0)[(size_t)srci * 256 + lane * 4]);

    #pragma unroll 2
    for (int i = beg; i < end; ++i) {
      float ev = ev_c;
      ushort4 f = f_c;
      if (i + 1 < end) {           // prefetch edge i+1
        int s2 = slots[i + 1];
        int srci2 = s2 & 0x7fffffff;
        ev_c = ((s2 < 0) ? el1 : el0)[(size_t)srci2 * 8 + h];
        f_c = *(const ushort4*)(&((s2 < 0) ? ft1 : ft0)[(size_t)srci2 * 256 + lane * 4]);
      }
      float v = ev + ern;
      v = (v >= 0.f) ? v : NEG_SLOPE * v;
      float w = __expf(v);
      sw += w;
      o0 = fmaf(w, bf2f(f.x), o0);
      o1 = fmaf(w, bf2f(f.y), o1);
      o2 = fmaf(w, bf2f(f.z), o2);
      o3 = fmaf(w, bf2f(f.w), o3);
    }
    float inv = 1.0f / sw;
    o0 *= inv; o1 *= inv; o2 *= inv; o3 *= inv;
  }
  *(float4*)(&rst[(size_t)n * 256 + lane * 4]) = make_float4(o0, o1, o2, o3);
}

// ---------------------------------------------------------------------------
extern "C" void kernel_launch(void* const* d_in, const int* in_sizes, int n_in,
                              void* d_out, int out_size, void* d_ws, size_t ws_size,
                              hipStream_t stream) {
  const float* master = (const float*)d_in[0];
  const float* af0    = (const float*)d_in[1];
  const float* af1    = (const float*)d_in[2];
  const int*   src0   = (const int*)d_in[3];
  const int*   dst0   = (const int*)d_in[4];
  const int*   src1   = (const int*)d_in[5];
  const int*   dst1   = (const int*)d_in[6];
  const float* Wm     = (const float*)d_in[7];
  const float* W0     = (const float*)d_in[8];
  const float* W1     = (const float*)d_in[9];
  const float* attn_l = (const float*)d_in[10];
  const float* attn_r = (const float*)d_in[11];

  const int Nm  = in_sizes[0] / 128;
  const int Na0 = in_sizes[1] / 128;
  const int Na1 = in_sizes[2] / 128;
  const int E0  = in_sizes[3];
  const int E1  = in_sizes[5];
  float* rst = (float*)d_out;

  char* ws = (char*)d_ws;
  size_t off = 0;
  auto alloc = [&](size_t b) -> char* {
    char* p = ws + off;
    off += (b + 511) & ~(size_t)511;
    return p;
  };
  unsigned short* ft0 = (unsigned short*)alloc((size_t)Na0 * 256 * sizeof(unsigned short));
  unsigned short* ft1 = (unsigned short*)alloc((size_t)Na1 * 256 * sizeof(unsigned short));
  float* el0 = (float*)alloc((size_t)Na0 * 8 * sizeof(float));
  float* el1 = (float*)alloc((size_t)Na1 * 8 * sizeof(float));
  float* er  = (float*)alloc((size_t)Nm * 8 * sizeof(float));
  int* deg    = (int*)alloc((size_t)Nm * sizeof(int));
  int* offs   = (int*)alloc((size_t)(Nm + 1) * sizeof(int));
  int* cursor = (int*)alloc((size_t)Nm * sizeof(int));
  int* slots  = (int*)alloc((size_t)(E0 + E1) * sizeof(int));

  proj_kernel<<<dim3((Nm  + 63) / 64, 4), 256, 0, stream>>>(master, Wm, attn_r, Nm,  nullptr, er);
  proj_kernel<<<dim3((Na0 + 63) / 64, 4), 256, 0, stream>>>(af0,    W0, attn_l, Na0, ft0,     el0);
  proj_kernel<<<dim3((Na1 + 63) / 64, 4), 256, 0, stream>>>(af1,    W1, attn_l, Na1, ft1,     el1);

  hipMemsetAsync(deg, 0, (size_t)Nm * sizeof(int), stream);
  count_deg_kernel<<<1024, 256, 0, stream>>>(dst0, E0, dst1, E1, deg);
  scan_kernel<<<1, 1024, 0, stream>>>(deg, offs, cursor, Nm);
  scatter_kernel<<<1024, 256, 0, stream>>>(src0, dst0, E0, src1, dst1, E1, cursor, slots);

  aggregate_kernel<<<(Nm + 3) / 4, 256, 0, stream>>>(offs, slots, el0, el1, er,
                                                     ft0, ft1, rst, Nm);
}

// Round 3
// 390.531 us; speedup vs baseline: 1.3424x; 1.2852x over previous
//
#include <hip/hip_runtime.h>
#include <cstdint>
#include <cstddef>

#define NEG_SLOPE 0.2f

static __device__ __forceinline__ unsigned short f2bf(float x) {
  uint32_t u = __float_as_uint(x);
  uint32_t r = (u + 0x7FFFu + ((u >> 16) & 1u)) >> 16;
  return (unsigned short)r;
}
static __device__ __forceinline__ float bf2f(unsigned short b) {
  return __uint_as_float(((uint32_t)b) << 16);
}

// ---------------------------------------------------------------------------
// proj: ft[N,256] = feats[N,128] @ W[128,256]  (optional bf16 store)
//       el[N,8]   = sum_d ft[n,h,d] * av[h,d]
// block 256 threads; tile 64 rows x 64 cols (blockIdx.y = col quad);
// thread tile 4x4. LDS: Ws[128][64] (32KB) + Fs[64][128] rotated (32KB).
// ---------------------------------------------------------------------------
__global__ __launch_bounds__(256)
void proj_kernel(const float* __restrict__ feats, const float* __restrict__ W,
                 const float* __restrict__ av, int N,
                 unsigned short* __restrict__ ft_out, float* __restrict__ el_out) {
  __shared__ float Ws[128][64];
  __shared__ float Fs[64][128];   // Fs[r][(k + 4r) & 127] = feats[rb+r][k]
  const int t = threadIdx.x;
  const int rb = blockIdx.x * 64;
  const int cb = blockIdx.y * 64;

  for (int i = t; i < 128 * 16; i += 256) {
    int k = i >> 4, c4 = (i & 15) << 2;
    *(float4*)(&Ws[k][c4]) = *(const float4*)(&W[k * 256 + cb + c4]);
  }
  for (int i = t; i < 64 * 32; i += 256) {
    int r = i >> 5, kc = (i & 31) << 2;
    float4 f = make_float4(0.f, 0.f, 0.f, 0.f);
    if (rb + r < N) f = *(const float4*)(&feats[(size_t)(rb + r) * 128 + kc]);
    *(float4*)(&Fs[r][(kc + 4 * r) & 127]) = f;
  }
  __syncthreads();

  const int rg = t >> 4;
  const int cg = t & 15;
  float acc[4][4] = {};

  #pragma unroll 2
  for (int k4 = 0; k4 < 128; k4 += 4) {
    float4 fv[4], wv[4];
    #pragma unroll
    for (int i = 0; i < 4; ++i) {
      int r = rg * 4 + i;
      fv[i] = *(const float4*)(&Fs[r][(k4 + 4 * r) & 127]);
    }
    #pragma unroll
    for (int kk = 0; kk < 4; ++kk)
      wv[kk] = *(const float4*)(&Ws[k4 + kk][cg * 4]);
    #pragma unroll
    for (int i = 0; i < 4; ++i) {
      const float fa[4] = {fv[i].x, fv[i].y, fv[i].z, fv[i].w};
      #pragma unroll
      for (int kk = 0; kk < 4; ++kk) {
        const float wa[4] = {wv[kk].x, wv[kk].y, wv[kk].z, wv[kk].w};
        acc[i][0] = fmaf(fa[kk], wa[0], acc[i][0]);
        acc[i][1] = fmaf(fa[kk], wa[1], acc[i][1]);
        acc[i][2] = fmaf(fa[kk], wa[2], acc[i][2]);
        acc[i][3] = fmaf(fa[kk], wa[3], acc[i][3]);
      }
    }
  }

  const int colg = cb + cg * 4;
  const int head = colg >> 5;
  const int d0 = colg & 31;
  float av4[4];
  #pragma unroll
  for (int j = 0; j < 4; ++j) av4[j] = av[head * 32 + d0 + j];

  #pragma unroll
  for (int i = 0; i < 4; ++i) {
    int row = rb + rg * 4 + i;
    bool ok = row < N;
    float p = 0.f;
    #pragma unroll
    for (int j = 0; j < 4; ++j) p = fmaf(acc[i][j], av4[j], p);
    p += __shfl_xor(p, 1);
    p += __shfl_xor(p, 2);
    p += __shfl_xor(p, 4);
    if (ok) {
      if (ft_out != nullptr) {
        ushort4 u;
        u.x = f2bf(acc[i][0]); u.y = f2bf(acc[i][1]);
        u.z = f2bf(acc[i][2]); u.w = f2bf(acc[i][3]);
        *(ushort4*)(&ft_out[(size_t)row * 256 + colg]) = u;
      }
      if ((cg & 7) == 0) el_out[(size_t)row * 8 + head] = p;
    }
  }
}

// ---------------------------------------------------------------------------
__global__ void count_deg_kernel(const int* __restrict__ dst0, int E0,
                                 const int* __restrict__ dst1, int E1,
                                 int* __restrict__ deg) {
  int E = E0 + E1;
  for (int i = blockIdx.x * blockDim.x + threadIdx.x; i < E;
       i += gridDim.x * blockDim.x) {
    int d = (i < E0) ? dst0[i] : dst1[i - E0];
    atomicAdd(&deg[d], 1);
  }
}

// ---------------------------------------------------------------------------
// Hierarchical scan: block_reduce -> partial_scan (1 wave) -> apply_scan.
// All phases coalesced and multi-block (the round-2 single-block scan was
// 126 us of naked uncoalesced L2 latency at 0.15% occupancy).
// ---------------------------------------------------------------------------
__global__ __launch_bounds__(1024)
void block_reduce_kernel(const int* __restrict__ deg, int* __restrict__ partial, int n) {
  __shared__ int wsum[16];
  const int t = threadIdx.x;
  int idx = blockIdx.x * 1024 + t;
  int v = (idx < n) ? deg[idx] : 0;
  #pragma unroll
  for (int off = 1; off < 64; off <<= 1) v += __shfl_xor(v, off);
  if ((t & 63) == 0) wsum[t >> 6] = v;
  __syncthreads();
  if (t < 16) {
    int x = wsum[t];
    #pragma unroll
    for (int off = 1; off < 16; off <<= 1) x += __shfl_xor(x, off);
    if (t == 0) partial[blockIdx.x] = x;
  }
}

// single wave: scan up to 64 block partials; write exclusive bases + total.
__global__ __launch_bounds__(64)
void partial_scan_kernel(const int* __restrict__ partial, int* __restrict__ base,
                         int nb, int* __restrict__ offs, int n) {
  const int t = threadIdx.x;
  int v = (t < nb) ? partial[t] : 0;
  int incl = v;
  #pragma unroll
  for (int off = 1; off < 64; off <<= 1) {
    int x = __shfl_up(incl, off);
    if (t >= off) incl += x;
  }
  if (t < nb) base[t] = incl - v;    // exclusive base for block t
  if (t == nb - 1) offs[n] = incl;   // total edges
}

__global__ __launch_bounds__(1024)
void apply_scan_kernel(const int* __restrict__ deg, const int* __restrict__ base,
                       int* __restrict__ offs, int* __restrict__ cursor, int n) {
  __shared__ int wsum[16];
  const int t = threadIdx.x;
  const int idx = blockIdx.x * 1024 + t;
  int v = (idx < n) ? deg[idx] : 0;
  const int lane = t & 63, w = t >> 6;
  int incl = v;
  #pragma unroll
  for (int off = 1; off < 64; off <<= 1) {
    int x = __shfl_up(incl, off);
    if (lane >= off) incl += x;
  }
  if (lane == 63) wsum[w] = incl;
  __syncthreads();
  if (t < 16) {
    int x = wsum[t];
    #pragma unroll
    for (int off = 1; off < 16; off <<= 1) {
      int y = __shfl_up(x, off);
      if (t >= off) x += y;
    }
    wsum[t] = x;
  }
  __syncthreads();
  int excl = base[blockIdx.x] + ((w > 0) ? wsum[w - 1] : 0) + incl - v;
  if (idx < n) {
    offs[idx] = excl;
    cursor[idx] = excl;
  }
}

__global__ void scatter_kernel(const int* __restrict__ src0, const int* __restrict__ dst0, int E0,
                               const int* __restrict__ src1, const int* __restrict__ dst1, int E1,
                               int* __restrict__ cursor, int* __restrict__ slots) {
  int E = E0 + E1;
  for (int i = blockIdx.x * blockDim.x + threadIdx.x; i < E;
       i += gridDim.x * blockDim.x) {
    int s, d, f;
    if (i < E0) { s = src0[i]; d = dst0[i]; f = 0; }
    else        { s = src1[i - E0]; d = dst1[i - E0]; f = 1; }
    int pos = atomicAdd(&cursor[d], 1);
    slots[pos] = s | (f << 31);
  }
}

// ---------------------------------------------------------------------------
// one wave per dst node, SINGLE pass: softmax without max-subtraction
// (logits = lrelu(el+er) are O(1)-bounded; exp cannot overflow; ratio is
// mathematically identical to the max-subtracted form).
// lane layout: flat = lane*4 -> h = lane>>3, d = (lane&7)*4 + j
// 1-deep software prefetch of next edge's el/ft hides part of L2/L3 latency.
// ---------------------------------------------------------------------------
__global__ __launch_bounds__(256)
void aggregate_kernel(const int* __restrict__ offs, const int* __restrict__ slots,
                      const float* __restrict__ el0, const float* __restrict__ el1,
                      const float* __restrict__ er,
                      const unsigned short* __restrict__ ft0,
                      const unsigned short* __restrict__ ft1,
                      float* __restrict__ rst, int Nm) {
  int gid = blockIdx.x * blockDim.x + threadIdx.x;
  int n = gid >> 6;
  int lane = threadIdx.x & 63;
  if (n >= Nm) return;
  int beg = offs[n], end = offs[n + 1];
  int h = lane >> 3;
  float o0 = 0.f, o1 = 0.f, o2 = 0.f, o3 = 0.f;
  if (beg < end) {
    float ern = er[(size_t)n * 8 + h];
    float sw = 0.f;

    int s = slots[beg];
    int srci = s & 0x7fffffff;
    float ev_c = ((s < 0) ? el1 : el0)[(size_t)srci * 8 + h];
    ushort4 f_c = *(const ushort4*)(&((s < 0) ? ft1 : ft0)[(size_t)srci * 256 + lane * 4]);

    #pragma unroll 2
    for (int i = beg; i < end; ++i) {
      float ev = ev_c;
      ushort4 f = f_c;
      if (i + 1 < end) {
        int s2 = slots[i + 1];
        int srci2 = s2 & 0x7fffffff;
        ev_c = ((s2 < 0) ? el1 : el0)[(size_t)srci2 * 8 + h];
        f_c = *(const ushort4*)(&((s2 < 0) ? ft1 : ft0)[(size_t)srci2 * 256 + lane * 4]);
      }
      float v = ev + ern;
      v = (v >= 0.f) ? v : NEG_SLOPE * v;
      float w = __expf(v);
      sw += w;
      o0 = fmaf(w, bf2f(f.x), o0);
      o1 = fmaf(w, bf2f(f.y), o1);
      o2 = fmaf(w, bf2f(f.z), o2);
      o3 = fmaf(w, bf2f(f.w), o3);
    }
    float inv = 1.0f / sw;
    o0 *= inv; o1 *= inv; o2 *= inv; o3 *= inv;
  }
  *(float4*)(&rst[(size_t)n * 256 + lane * 4]) = make_float4(o0, o1, o2, o3);
}

// ---------------------------------------------------------------------------
extern "C" void kernel_launch(void* const* d_in, const int* in_sizes, int n_in,
                              void* d_out, int out_size, void* d_ws, size_t ws_size,
                              hipStream_t stream) {
  const float* master = (const float*)d_in[0];
  const float* af0    = (const float*)d_in[1];
  const float* af1    = (const float*)d_in[2];
  const int*   src0   = (const int*)d_in[3];
  const int*   dst0   = (const int*)d_in[4];
  const int*   src1   = (const int*)d_in[5];
  const int*   dst1   = (const int*)d_in[6];
  const float* Wm     = (const float*)d_in[7];
  const float* W0     = (const float*)d_in[8];
  const float* W1     = (const float*)d_in[9];
  const float* attn_l = (const float*)d_in[10];
  const float* attn_r = (const float*)d_in[11];

  const int Nm  = in_sizes[0] / 128;
  const int Na0 = in_sizes[1] / 128;
  const int Na1 = in_sizes[2] / 128;
  const int E0  = in_sizes[3];
  const int E1  = in_sizes[5];
  float* rst = (float*)d_out;

  char* ws = (char*)d_ws;
  size_t off = 0;
  auto alloc = [&](size_t b) -> char* {
    char* p = ws + off;
    off += (b + 511) & ~(size_t)511;
    return p;
  };
  unsigned short* ft0 = (unsigned short*)alloc((size_t)Na0 * 256 * sizeof(unsigned short));
  unsigned short* ft1 = (unsigned short*)alloc((size_t)Na1 * 256 * sizeof(unsigned short));
  float* el0 = (float*)alloc((size_t)Na0 * 8 * sizeof(float));
  float* el1 = (float*)alloc((size_t)Na1 * 8 * sizeof(float));
  float* er  = (float*)alloc((size_t)Nm * 8 * sizeof(float));
  int* deg     = (int*)alloc((size_t)Nm * sizeof(int));
  int* offs    = (int*)alloc((size_t)(Nm + 1) * sizeof(int));
  int* cursor  = (int*)alloc((size_t)Nm * sizeof(int));
  int* partial = (int*)alloc(64 * sizeof(int));
  int* pbase   = (int*)alloc(64 * sizeof(int));
  int* slots   = (int*)alloc((size_t)(E0 + E1) * sizeof(int));

  proj_kernel<<<dim3((Nm  + 63) / 64, 4), 256, 0, stream>>>(master, Wm, attn_r, Nm,  nullptr, er);
  proj_kernel<<<dim3((Na0 + 63) / 64, 4), 256, 0, stream>>>(af0,    W0, attn_l, Na0, ft0,     el0);
  proj_kernel<<<dim3((Na1 + 63) / 64, 4), 256, 0, stream>>>(af1,    W1, attn_l, Na1, ft1,     el1);

  hipMemsetAsync(deg, 0, (size_t)Nm * sizeof(int), stream);
  count_deg_kernel<<<1024, 256, 0, stream>>>(dst0, E0, dst1, E1, deg);

  const int nb = (Nm + 1023) / 1024;   // <= 64 required by partial_scan
  block_reduce_kernel<<<nb, 1024, 0, stream>>>(deg, partial, Nm);
  partial_scan_kernel<<<1, 64, 0, stream>>>(partial, pbase, nb, offs, Nm);
  apply_scan_kernel<<<nb, 1024, 0, stream>>>(deg, pbase, offs, cursor, Nm);

  scatter_kernel<<<1024, 256, 0, stream>>>(src0, dst0, E0, src1, dst1, E1, cursor, slots);

  aggregate_kernel<<<(Nm + 3) / 4, 256, 0, stream>>>(offs, slots, el0, el1, er,
                                                     ft0, ft1, rst, Nm);
}

// Round 4
// 284.438 us; speedup vs baseline: 1.8432x; 1.3730x over previous
//
#include <hip/hip_runtime.h>
#include <cstdint>
#include <cstddef>

#define NEG_SLOPE 0.2f

typedef __attribute__((ext_vector_type(8))) short short8;
typedef __attribute__((ext_vector_type(4))) float f32x4;

static __device__ __forceinline__ unsigned short f2bf(float x) {
  uint32_t u = __float_as_uint(x);
  uint32_t r = (u + 0x7FFFu + ((u >> 16) & 1u)) >> 16;
  return (unsigned short)r;
}
static __device__ __forceinline__ float bf2f(unsigned short b) {
  return __uint_as_float(((uint32_t)b) << 16);
}

// ---------------------------------------------------------------------------
// W[128][256] f32 -> Wt[256][128] bf16, x3 weight matrices (blockIdx.y).
// Coalesced writes; scattered reads are L2-resident (W = 128 KB).
// ---------------------------------------------------------------------------
__global__ void wt_kernel(const float* __restrict__ W0, const float* __restrict__ W1,
                          const float* __restrict__ W2,
                          unsigned short* __restrict__ T0, unsigned short* __restrict__ T1,
                          unsigned short* __restrict__ T2) {
  const float* W = (blockIdx.y == 0) ? W0 : (blockIdx.y == 1) ? W1 : W2;
  unsigned short* T = (blockIdx.y == 0) ? T0 : (blockIdx.y == 1) ? T1 : T2;
  int c = blockIdx.x * 2 + (threadIdx.x >> 7);   // 0..255
  int k = threadIdx.x & 127;                     // 0..127
  T[c * 128 + k] = f2bf(W[k * 256 + c]);
}

// ---------------------------------------------------------------------------
// MFMA proj: ft[N,256] = bf16(feats[N,128]) @ bf16(W[128,256]) (fp32 acc)
//            el[N,8]   = sum_d ft[n,h,d] * av[h,d]   (fused epilogue)
// Block 256 thr = 4 waves (2x2), block tile 128x128, wave tile 64x64.
// LDS: As[128][128] bf16 + Bs(=Wt cols)[128][128] bf16, both XOR-swizzled
// (byte ^= (row&7)<<4) so the stride-256B fragment reads are conflict-free.
// Fragment maps (m92/m97-verified): A row=l&15, k=8*(l>>4)+j (contiguous 8);
// B col=l&15, same k; C col=l&15, row=(l>>4)*4+reg.
// ---------------------------------------------------------------------------
__global__ __launch_bounds__(256)
void proj_mfma_kernel(const float* __restrict__ feats,
                      const unsigned short* __restrict__ Wt,
                      const float* __restrict__ av, int N,
                      unsigned short* __restrict__ ft_out,
                      float* __restrict__ el_out) {
  __shared__ unsigned short As[128 * 128];
  __shared__ unsigned short Bs[128 * 128];
  const int t = threadIdx.x;
  const int rb = blockIdx.x * 128;
  const int cb = blockIdx.y * 128;

  // stage A: f32 -> bf16, swizzled
  #pragma unroll
  for (int it = 0; it < 16; ++it) {
    int i = it * 256 + t;
    int r = i >> 5, kc = (i & 31) << 2;
    float4 f = make_float4(0.f, 0.f, 0.f, 0.f);
    if (rb + r < N) f = *(const float4*)(&feats[(size_t)(rb + r) * 128 + kc]);
    ushort4 u;
    u.x = f2bf(f.x); u.y = f2bf(f.y); u.z = f2bf(f.z); u.w = f2bf(f.w);
    uint32_t byte = ((uint32_t)(r * 256 + kc * 2)) ^ ((uint32_t)((r & 7) << 4));
    *(ushort4*)((char*)As + byte) = u;
  }
  // stage B: Wt rows cb..cb+128 (bf16 already), swizzled
  #pragma unroll
  for (int it = 0; it < 8; ++it) {
    int i = it * 256 + t;
    int c = i >> 4, k8 = (i & 15) << 3;
    short8 w = *(const short8*)(&Wt[(size_t)(cb + c) * 128 + k8]);
    uint32_t byte = ((uint32_t)(c * 256 + k8 * 2)) ^ ((uint32_t)((c & 7) << 4));
    *(short8*)((char*)Bs + byte) = w;
  }
  __syncthreads();

  const int wid = t >> 6, lane = t & 63;
  const int wm = wid >> 1, wn = wid & 1;
  const int l15 = lane & 15, l4 = lane >> 4;

  f32x4 acc[4][4];
  #pragma unroll
  for (int a = 0; a < 4; ++a)
    #pragma unroll
    for (int b = 0; b < 4; ++b)
      acc[a][b] = (f32x4){0.f, 0.f, 0.f, 0.f};

  #pragma unroll
  for (int kb = 0; kb < 4; ++kb) {
    const uint32_t kbyte = (uint32_t)(kb * 64 + l4 * 16);
    short8 af[4], bf[4];
    #pragma unroll
    for (int mf = 0; mf < 4; ++mf) {
      int row = wm * 64 + mf * 16 + l15;
      uint32_t byte = ((uint32_t)(row * 256) + kbyte) ^ ((uint32_t)((row & 7) << 4));
      af[mf] = *(const short8*)((const char*)As + byte);
    }
    #pragma unroll
    for (int nf = 0; nf < 4; ++nf) {
      int col = wn * 64 + nf * 16 + l15;
      uint32_t byte = ((uint32_t)(col * 256) + kbyte) ^ ((uint32_t)((col & 7) << 4));
      bf[nf] = *(const short8*)((const char*)Bs + byte);
    }
    #pragma unroll
    for (int mf = 0; mf < 4; ++mf)
      #pragma unroll
      for (int nf = 0; nf < 4; ++nf)
        acc[mf][nf] = __builtin_amdgcn_mfma_f32_16x16x32_bf16(af[mf], bf[nf], acc[mf][nf], 0, 0, 0);
  }

  // epilogue: ft store (bf16) + fused el/er dot (two heads per wave)
  const int cbw = cb + wn * 64;
  const int head0 = cbw >> 5;
  float avv[4];
  #pragma unroll
  for (int nf = 0; nf < 4; ++nf)
    avv[nf] = av[(head0 + (nf >> 1)) * 32 + (nf & 1) * 16 + l15];

  #pragma unroll
  for (int mf = 0; mf < 4; ++mf) {
    const int rowb = rb + wm * 64 + mf * 16;
    if (ft_out != nullptr) {
      #pragma unroll
      for (int reg = 0; reg < 4; ++reg) {
        int row = rowb + l4 * 4 + reg;
        if (row < N) {
          size_t base = (size_t)row * 256 + cbw;
          #pragma unroll
          for (int nf = 0; nf < 4; ++nf)
            ft_out[base + nf * 16 + l15] = f2bf(acc[mf][nf][reg]);
        }
      }
    }
    #pragma unroll
    for (int hh = 0; hh < 2; ++hh) {
      float v[4];
      #pragma unroll
      for (int reg = 0; reg < 4; ++reg) {
        float p = fmaf(acc[mf][2 * hh][reg], avv[2 * hh],
                       acc[mf][2 * hh + 1][reg] * avv[2 * hh + 1]);
        p += __shfl_xor(p, 1);
        p += __shfl_xor(p, 2);
        p += __shfl_xor(p, 4);
        p += __shfl_xor(p, 8);
        v[reg] = p;
      }
      if (l15 < 4) {
        int row = rowb + l4 * 4 + l15;
        if (row < N) {
          float val = (l15 == 0) ? v[0] : (l15 == 1) ? v[1] : (l15 == 2) ? v[2] : v[3];
          el_out[(size_t)row * 8 + head0 + hh] = val;
        }
      }
    }
  }
}

// ---------------------------------------------------------------------------
__global__ void count_deg_kernel(const int* __restrict__ dst0, int E0,
                                 const int* __restrict__ dst1, int E1,
                                 int* __restrict__ deg) {
  int E = E0 + E1;
  for (int i = blockIdx.x * blockDim.x + threadIdx.x; i < E;
       i += gridDim.x * blockDim.x) {
    int d = (i < E0) ? dst0[i] : dst1[i - E0];
    atomicAdd(&deg[d], 1);
  }
}

__global__ __launch_bounds__(1024)
void block_reduce_kernel(const int* __restrict__ deg, int* __restrict__ partial, int n) {
  __shared__ int wsum[16];
  const int t = threadIdx.x;
  int idx = blockIdx.x * 1024 + t;
  int v = (idx < n) ? deg[idx] : 0;
  #pragma unroll
  for (int off = 1; off < 64; off <<= 1) v += __shfl_xor(v, off);
  if ((t & 63) == 0) wsum[t >> 6] = v;
  __syncthreads();
  if (t < 16) {
    int x = wsum[t];
    #pragma unroll
    for (int off = 1; off < 16; off <<= 1) x += __shfl_xor(x, off);
    if (t == 0) partial[blockIdx.x] = x;
  }
}

__global__ __launch_bounds__(64)
void partial_scan_kernel(const int* __restrict__ partial, int* __restrict__ base,
                         int nb, int* __restrict__ offs, int n) {
  const int t = threadIdx.x;
  int v = (t < nb) ? partial[t] : 0;
  int incl = v;
  #pragma unroll
  for (int off = 1; off < 64; off <<= 1) {
    int x = __shfl_up(incl, off);
    if (t >= off) incl += x;
  }
  if (t < nb) base[t] = incl - v;
  if (t == nb - 1) offs[n] = incl;
}

__global__ __launch_bounds__(1024)
void apply_scan_kernel(const int* __restrict__ deg, const int* __restrict__ base,
                       int* __restrict__ offs, int* __restrict__ cursor, int n) {
  __shared__ int wsum[16];
  const int t = threadIdx.x;
  const int idx = blockIdx.x * 1024 + t;
  int v = (idx < n) ? deg[idx] : 0;
  const int lane = t & 63, w = t >> 6;
  int incl = v;
  #pragma unroll
  for (int off = 1; off < 64; off <<= 1) {
    int x = __shfl_up(incl, off);
    if (lane >= off) incl += x;
  }
  if (lane == 63) wsum[w] = incl;
  __syncthreads();
  if (t < 16) {
    int x = wsum[t];
    #pragma unroll
    for (int off = 1; off < 16; off <<= 1) {
      int y = __shfl_up(x, off);
      if (t >= off) x += y;
    }
    wsum[t] = x;
  }
  __syncthreads();
  int excl = base[blockIdx.x] + ((w > 0) ? wsum[w - 1] : 0) + incl - v;
  if (idx < n) {
    offs[idx] = excl;
    cursor[idx] = excl;
  }
}

// slot stores MERGED source index (srci + flag*Na0) -> no per-edge selects.
__global__ void scatter_kernel(const int* __restrict__ src0, const int* __restrict__ dst0, int E0,
                               const int* __restrict__ src1, const int* __restrict__ dst1, int E1,
                               int* __restrict__ cursor, int* __restrict__ slots, int Na0) {
  int E = E0 + E1;
  for (int i = blockIdx.x * blockDim.x + threadIdx.x; i < E;
       i += gridDim.x * blockDim.x) {
    int s, d;
    if (i < E0) { s = src0[i]; d = dst0[i]; }
    else        { s = src1[i - E0] + Na0; d = dst1[i - E0]; }
    int pos = atomicAdd(&cursor[d], 1);
    slots[pos] = s;
  }
}

// ---------------------------------------------------------------------------
// one wave per dst node, single pass (no max-subtraction: lrelu logits are
// O(1)-bounded so exp cannot overflow; ratio is mathematically identical).
// Merged el/ft tables; 2-deep software prefetch.
// lane layout: h = lane>>3, d = (lane&7)*4 + j
// ---------------------------------------------------------------------------
__global__ __launch_bounds__(256)
void aggregate_kernel(const int* __restrict__ offs, const int* __restrict__ slots,
                      const float* __restrict__ el, const float* __restrict__ er,
                      const unsigned short* __restrict__ ft,
                      float* __restrict__ rst, int Nm) {
  int gid = blockIdx.x * blockDim.x + threadIdx.x;
  int n = gid >> 6;
  int lane = threadIdx.x & 63;
  if (n >= Nm) return;
  int beg = offs[n], end = offs[n + 1];
  int h = lane >> 3;
  float o0 = 0.f, o1 = 0.f, o2 = 0.f, o3 = 0.f;
  if (beg < end) {
    float ern = er[(size_t)n * 8 + h];
    float sw = 0.f;

    int iA = slots[beg];
    float eA = el[(size_t)iA * 8 + h];
    ushort4 fA = *(const ushort4*)((const char*)ft + (((size_t)(uint32_t)iA) << 9) + lane * 8);
    float eB = 0.f;
    ushort4 fB = fA;
    if (beg + 1 < end) {
      int iB = slots[beg + 1];
      eB = el[(size_t)iB * 8 + h];
      fB = *(const ushort4*)((const char*)ft + (((size_t)(uint32_t)iB) << 9) + lane * 8);
    }

    for (int i = beg; i < end; ++i) {
      float ev = eA;
      ushort4 f = fA;
      eA = eB; fA = fB;
      if (i + 2 < end) {
        int iC = slots[i + 2];
        eB = el[(size_t)iC * 8 + h];
        fB = *(const ushort4*)((const char*)ft + (((size_t)(uint32_t)iC) << 9) + lane * 8);
      }
      float v = ev + ern;
      v = fmaxf(v, NEG_SLOPE * v);          // leaky relu
      float w = __expf(v);
      sw += w;
      o0 = fmaf(w, bf2f(f.x), o0);
      o1 = fmaf(w, bf2f(f.y), o1);
      o2 = fmaf(w, bf2f(f.z), o2);
      o3 = fmaf(w, bf2f(f.w), o3);
    }
    float inv = 1.0f / sw;
    o0 *= inv; o1 *= inv; o2 *= inv; o3 *= inv;
  }
  *(float4*)(&rst[(size_t)n * 256 + lane * 4]) = make_float4(o0, o1, o2, o3);
}

// ---------------------------------------------------------------------------
extern "C" void kernel_launch(void* const* d_in, const int* in_sizes, int n_in,
                              void* d_out, int out_size, void* d_ws, size_t ws_size,
                              hipStream_t stream) {
  const float* master = (const float*)d_in[0];
  const float* af0    = (const float*)d_in[1];
  const float* af1    = (const float*)d_in[2];
  const int*   src0   = (const int*)d_in[3];
  const int*   dst0   = (const int*)d_in[4];
  const int*   src1   = (const int*)d_in[5];
  const int*   dst1   = (const int*)d_in[6];
  const float* Wm     = (const float*)d_in[7];
  const float* W0     = (const float*)d_in[8];
  const float* W1     = (const float*)d_in[9];
  const float* attn_l = (const float*)d_in[10];
  const float* attn_r = (const float*)d_in[11];

  const int Nm  = in_sizes[0] / 128;
  const int Na0 = in_sizes[1] / 128;
  const int Na1 = in_sizes[2] / 128;
  const int E0  = in_sizes[3];
  const int E1  = in_sizes[5];
  float* rst = (float*)d_out;

  char* ws = (char*)d_ws;
  size_t off = 0;
  auto alloc = [&](size_t b) -> char* {
    char* p = ws + off;
    off += (b + 511) & ~(size_t)511;
    return p;
  };
  unsigned short* ft = (unsigned short*)alloc((size_t)(Na0 + Na1) * 256 * sizeof(unsigned short));
  float* el = (float*)alloc((size_t)(Na0 + Na1) * 8 * sizeof(float));
  float* er = (float*)alloc((size_t)Nm * 8 * sizeof(float));
  unsigned short* Wtm = (unsigned short*)alloc(256 * 128 * sizeof(unsigned short));
  unsigned short* Wt0 = (unsigned short*)alloc(256 * 128 * sizeof(unsigned short));
  unsigned short* Wt1 = (unsigned short*)alloc(256 * 128 * sizeof(unsigned short));
  int* deg     = (int*)alloc((size_t)Nm * sizeof(int));
  int* offs    = (int*)alloc((size_t)(Nm + 1) * sizeof(int));
  int* cursor  = (int*)alloc((size_t)Nm * sizeof(int));
  int* partial = (int*)alloc(64 * sizeof(int));
  int* pbase   = (int*)alloc(64 * sizeof(int));
  int* slots   = (int*)alloc((size_t)(E0 + E1) * sizeof(int));

  // weight transpose+cast (tiny, L2-resident)
  wt_kernel<<<dim3(128, 3), 256, 0, stream>>>(Wm, W0, W1, Wtm, Wt0, Wt1);

  // MFMA projections, el/er fused in epilogue
  const int mb_m  = (Nm  + 127) / 128;
  const int mb_a0 = (Na0 + 127) / 128;
  const int mb_a1 = (Na1 + 127) / 128;
  proj_mfma_kernel<<<dim3(mb_m, 2), 256, 0, stream>>>(master, Wtm, attn_r, Nm, nullptr, er);
  proj_mfma_kernel<<<dim3(mb_a0, 2), 256, 0, stream>>>(af0, Wt0, attn_l, Na0, ft, el);
  proj_mfma_kernel<<<dim3(mb_a1, 2), 256, 0, stream>>>(af1, Wt1, attn_l, Na1,
                                                       ft + (size_t)Na0 * 256, el + (size_t)Na0 * 8);

  // CSR build over combined dst
  hipMemsetAsync(deg, 0, (size_t)Nm * sizeof(int), stream);
  count_deg_kernel<<<1024, 256, 0, stream>>>(dst0, E0, dst1, E1, deg);
  const int nb = (Nm + 1023) / 1024;   // <= 64
  block_reduce_kernel<<<nb, 1024, 0, stream>>>(deg, partial, Nm);
  partial_scan_kernel<<<1, 64, 0, stream>>>(partial, pbase, nb, offs, Nm);
  apply_scan_kernel<<<nb, 1024, 0, stream>>>(deg, pbase, offs, cursor, Nm);
  scatter_kernel<<<1024, 256, 0, stream>>>(src0, dst0, E0, src1, dst1, E1, cursor, slots, Na0);

  // per-node softmax + weighted aggregation
  aggregate_kernel<<<(Nm + 3) / 4, 256, 0, stream>>>(offs, slots, el, er, ft, rst, Nm);
}

// Round 5
// 265.692 us; speedup vs baseline: 1.9732x; 1.0706x over previous
//
#include <hip/hip_runtime.h>
#include <cstdint>
#include <cstddef>

#define NEG_SLOPE 0.2f

typedef __attribute__((ext_vector_type(8))) short short8;
typedef __attribute__((ext_vector_type(4))) float f32x4;

static __device__ __forceinline__ unsigned short f2bf(float x) {
  uint32_t u = __float_as_uint(x);
  uint32_t r = (u + 0x7FFFu + ((u >> 16) & 1u)) >> 16;
  return (unsigned short)r;
}
static __device__ __forceinline__ float bf2f(unsigned short b) {
  return __uint_as_float(((uint32_t)b) << 16);
}

// ---------------------------------------------------------------------------
// W[128][256] f32 -> Wt[256][128] bf16, x3 weight matrices (blockIdx.y).
// ---------------------------------------------------------------------------
__global__ void wt_kernel(const float* __restrict__ W0, const float* __restrict__ W1,
                          const float* __restrict__ W2,
                          unsigned short* __restrict__ T0, unsigned short* __restrict__ T1,
                          unsigned short* __restrict__ T2) {
  const float* W = (blockIdx.y == 0) ? W0 : (blockIdx.y == 1) ? W1 : W2;
  unsigned short* T = (blockIdx.y == 0) ? T0 : (blockIdx.y == 1) ? T1 : T2;
  int c = blockIdx.x * 2 + (threadIdx.x >> 7);   // 0..255
  int k = threadIdx.x & 127;                     // 0..127
  T[c * 128 + k] = f2bf(W[k * 256 + c]);
}

// ---------------------------------------------------------------------------
// Fused MFMA proj (z = which matrix): ft = bf16(feats) @ bf16(W), el fused.
// Block 256 thr = 4 waves (2x2), block tile 128x128, wave tile 64x64.
// LDS XOR-swizzle byte ^= (row&7)<<4 on both tiles (T2).
// Epilogue: acc -> bf16 via LDS (reuse As) -> coalesced short8 stores.
// ---------------------------------------------------------------------------
__global__ __launch_bounds__(256)
void proj_mfma_kernel(const float* __restrict__ fm, const float* __restrict__ fa0,
                      const float* __restrict__ fa1,
                      const unsigned short* __restrict__ Wtm,
                      const unsigned short* __restrict__ Wt0,
                      const unsigned short* __restrict__ Wt1,
                      const float* __restrict__ attn_l, const float* __restrict__ attn_r,
                      int Nm, int Na0, int Na1,
                      unsigned short* __restrict__ ft_all, float* __restrict__ el_all,
                      float* __restrict__ er) {
  const int z = blockIdx.z;
  const float* feats = (z == 0) ? fm : (z == 1) ? fa0 : fa1;
  const unsigned short* Wt = (z == 0) ? Wtm : (z == 1) ? Wt0 : Wt1;
  const float* av = (z == 0) ? attn_r : attn_l;
  const int N = (z == 0) ? Nm : (z == 1) ? Na0 : Na1;
  unsigned short* ft_out = (z == 0) ? nullptr
                         : (z == 1) ? ft_all : ft_all + (size_t)Na0 * 256;
  float* el_out = (z == 0) ? er : (z == 1) ? el_all : el_all + (size_t)Na0 * 8;

  const int rb = blockIdx.x * 128;
  if (rb >= N) return;
  const int cb = blockIdx.y * 128;

  __shared__ unsigned short As[128 * 128];
  __shared__ unsigned short Bs[128 * 128];
  const int t = threadIdx.x;

  #pragma unroll
  for (int it = 0; it < 16; ++it) {
    int i = it * 256 + t;
    int r = i >> 5, kc = (i & 31) << 2;
    float4 f = make_float4(0.f, 0.f, 0.f, 0.f);
    if (rb + r < N) f = *(const float4*)(&feats[(size_t)(rb + r) * 128 + kc]);
    ushort4 u;
    u.x = f2bf(f.x); u.y = f2bf(f.y); u.z = f2bf(f.z); u.w = f2bf(f.w);
    uint32_t byte = ((uint32_t)(r * 256 + kc * 2)) ^ ((uint32_t)((r & 7) << 4));
    *(ushort4*)((char*)As + byte) = u;
  }
  #pragma unroll
  for (int it = 0; it < 8; ++it) {
    int i = it * 256 + t;
    int c = i >> 4, k8 = (i & 15) << 3;
    short8 w = *(const short8*)(&Wt[(size_t)(cb + c) * 128 + k8]);
    uint32_t byte = ((uint32_t)(c * 256 + k8 * 2)) ^ ((uint32_t)((c & 7) << 4));
    *(short8*)((char*)Bs + byte) = w;
  }
  __syncthreads();

  const int wid = t >> 6, lane = t & 63;
  const int wm = wid >> 1, wn = wid & 1;
  const int l15 = lane & 15, l4 = lane >> 4;

  f32x4 acc[4][4];
  #pragma unroll
  for (int a = 0; a < 4; ++a)
    #pragma unroll
    for (int b = 0; b < 4; ++b)
      acc[a][b] = (f32x4){0.f, 0.f, 0.f, 0.f};

  #pragma unroll
  for (int kb = 0; kb < 4; ++kb) {
    const uint32_t kbyte = (uint32_t)(kb * 64 + l4 * 16);
    short8 af[4], bf[4];
    #pragma unroll
    for (int mf = 0; mf < 4; ++mf) {
      int row = wm * 64 + mf * 16 + l15;
      uint32_t byte = ((uint32_t)(row * 256) + kbyte) ^ ((uint32_t)((row & 7) << 4));
      af[mf] = *(const short8*)((const char*)As + byte);
    }
    #pragma unroll
    for (int nf = 0; nf < 4; ++nf) {
      int col = wn * 64 + nf * 16 + l15;
      uint32_t byte = ((uint32_t)(col * 256) + kbyte) ^ ((uint32_t)((col & 7) << 4));
      bf[nf] = *(const short8*)((const char*)Bs + byte);
    }
    #pragma unroll
    for (int mf = 0; mf < 4; ++mf)
      #pragma unroll
      for (int nf = 0; nf < 4; ++nf)
        acc[mf][nf] = __builtin_amdgcn_mfma_f32_16x16x32_bf16(af[mf], bf[nf], acc[mf][nf], 0, 0, 0);
  }

  // fused el/er dot (uses acc in regs; 2 heads per wave column-half)
  const int cbw = cb + wn * 64;
  const int head0 = cbw >> 5;
  float avv[4];
  #pragma unroll
  for (int nf = 0; nf < 4; ++nf)
    avv[nf] = av[(head0 + (nf >> 1)) * 32 + (nf & 1) * 16 + l15];

  #pragma unroll
  for (int mf = 0; mf < 4; ++mf) {
    const int rowb = rb + wm * 64 + mf * 16;
    #pragma unroll
    for (int hh = 0; hh < 2; ++hh) {
      float v[4];
      #pragma unroll
      for (int reg = 0; reg < 4; ++reg) {
        float p = fmaf(acc[mf][2 * hh][reg], avv[2 * hh],
                       acc[mf][2 * hh + 1][reg] * avv[2 * hh + 1]);
        p += __shfl_xor(p, 1);
        p += __shfl_xor(p, 2);
        p += __shfl_xor(p, 4);
        p += __shfl_xor(p, 8);
        v[reg] = p;
      }
      if (l15 < 4) {
        int row = rowb + l4 * 4 + l15;
        if (row < N) {
          float val = (l15 == 0) ? v[0] : (l15 == 1) ? v[1] : (l15 == 2) ? v[2] : v[3];
          el_out[(size_t)row * 8 + head0 + hh] = val;
        }
      }
    }
  }

  // ft epilogue through LDS: bf16 results -> As (swizzled) -> coalesced stores
  if (ft_out != nullptr) {
    __syncthreads();   // all waves done reading As/Bs
    #pragma unroll
    for (int mf = 0; mf < 4; ++mf)
      #pragma unroll
      for (int nf = 0; nf < 4; ++nf)
        #pragma unroll
        for (int reg = 0; reg < 4; ++reg) {
          int row = wm * 64 + mf * 16 + l4 * 4 + reg;
          int colb = (wn * 64 + nf * 16 + l15) * 2;
          uint32_t byte = ((uint32_t)(row * 256 + colb)) ^ ((uint32_t)((row & 7) << 4));
          *(unsigned short*)((char*)As + byte) = f2bf(acc[mf][nf][reg]);
        }
    __syncthreads();
    #pragma unroll
    for (int it = 0; it < 8; ++it) {
      int i = it * 256 + t;          // 0..2047
      int r = i >> 4, j = i & 15;    // row 0..127, 16B-block 0..15
      int pj = j ^ (r & 7);          // inverse swizzle (16B-granular XOR)
      short8 vv = *(const short8*)((const char*)As + r * 256 + pj * 16);
      if (rb + r < N)
        *(short8*)(&ft_out[(size_t)(rb + r) * 256 + cb + j * 8]) = vv;
    }
  }
}

// ---------------------------------------------------------------------------
__global__ void count_deg_kernel(const int* __restrict__ dst0, int E0,
                                 const int* __restrict__ dst1, int E1,
                                 int* __restrict__ deg) {
  int E = E0 + E1;
  for (int i = blockIdx.x * blockDim.x + threadIdx.x; i < E;
       i += gridDim.x * blockDim.x) {
    int d = (i < E0) ? dst0[i] : dst1[i - E0];
    atomicAdd(&deg[d], 1);
  }
}

__global__ __launch_bounds__(1024)
void block_reduce_kernel(const int* __restrict__ deg, int* __restrict__ partial, int n) {
  __shared__ int wsum[16];
  const int t = threadIdx.x;
  int idx = blockIdx.x * 1024 + t;
  int v = (idx < n) ? deg[idx] : 0;
  #pragma unroll
  for (int off = 1; off < 64; off <<= 1) v += __shfl_xor(v, off);
  if ((t & 63) == 0) wsum[t >> 6] = v;
  __syncthreads();
  if (t < 16) {
    int x = wsum[t];
    #pragma unroll
    for (int off = 1; off < 16; off <<= 1) x += __shfl_xor(x, off);
    if (t == 0) partial[blockIdx.x] = x;
  }
}

__global__ __launch_bounds__(64)
void partial_scan_kernel(const int* __restrict__ partial, int* __restrict__ base,
                         int nb, int* __restrict__ offs, int n) {
  const int t = threadIdx.x;
  int v = (t < nb) ? partial[t] : 0;
  int incl = v;
  #pragma unroll
  for (int off = 1; off < 64; off <<= 1) {
    int x = __shfl_up(incl, off);
    if (t >= off) incl += x;
  }
  if (t < nb) base[t] = incl - v;
  if (t == nb - 1) offs[n] = incl;
}

__global__ __launch_bounds__(1024)
void apply_scan_kernel(const int* __restrict__ deg, const int* __restrict__ base,
                       int* __restrict__ offs, int* __restrict__ cursor, int n) {
  __shared__ int wsum[16];
  const int t = threadIdx.x;
  const int idx = blockIdx.x * 1024 + t;
  int v = (idx < n) ? deg[idx] : 0;
  const int lane = t & 63, w = t >> 6;
  int incl = v;
  #pragma unroll
  for (int off = 1; off < 64; off <<= 1) {
    int x = __shfl_up(incl, off);
    if (lane >= off) incl += x;
  }
  if (lane == 63) wsum[w] = incl;
  __syncthreads();
  if (t < 16) {
    int x = wsum[t];
    #pragma unroll
    for (int off = 1; off < 16; off <<= 1) {
      int y = __shfl_up(x, off);
      if (t >= off) x += y;
    }
    wsum[t] = x;
  }
  __syncthreads();
  int excl = base[blockIdx.x] + ((w > 0) ? wsum[w - 1] : 0) + incl - v;
  if (idx < n) {
    offs[idx] = excl;
    cursor[idx] = excl;
  }
}

// slot stores MERGED source index (srci + flag*Na0).
__global__ void scatter_kernel(const int* __restrict__ src0, const int* __restrict__ dst0, int E0,
                               const int* __restrict__ src1, const int* __restrict__ dst1, int E1,
                               int* __restrict__ cursor, int* __restrict__ slots, int Na0) {
  int E = E0 + E1;
  for (int i = blockIdx.x * blockDim.x + threadIdx.x; i < E;
       i += gridDim.x * blockDim.x) {
    int s, d;
    if (i < E0) { s = src0[i]; d = dst0[i]; }
    else        { s = src1[i - E0] + Na0; d = dst1[i - E0]; }
    int pos = atomicAdd(&cursor[d], 1);
    slots[pos] = s;
  }
}

// ---------------------------------------------------------------------------
// one wave per dst node, single pass, 4-deep static software pipeline.
// beg/end are wave-uniform -> all stage guards are uniform s_cbranch.
// lane layout: h = lane>>3, d = (lane&7)*4 + j
// ---------------------------------------------------------------------------
__global__ __launch_bounds__(256)
void aggregate_kernel(const int* __restrict__ offs, const int* __restrict__ slots,
                      const float* __restrict__ el, const float* __restrict__ er,
                      const unsigned short* __restrict__ ft,
                      float* __restrict__ rst, int Nm) {
  int gid = blockIdx.x * blockDim.x + threadIdx.x;
  int n = gid >> 6;
  int lane = threadIdx.x & 63;
  if (n >= Nm) return;
  int beg = offs[n], end = offs[n + 1];
  int h = lane >> 3;
  float o0 = 0.f, o1 = 0.f, o2 = 0.f, o3 = 0.f;
  if (beg < end) {
    float ern = er[(size_t)n * 8 + h];
    float sw = 0.f;

    float e0 = 0.f, e1 = 0.f, e2 = 0.f, e3 = 0.f;
    ushort4 f0 = {0, 0, 0, 0}, f1 = f0, f2 = f0, f3 = f0;

#define LD(idx, ee, ff)                                                          \
    do {                                                                         \
      if ((idx) < end) {                                                         \
        int s_ = slots[(idx)];                                                   \
        ee = el[((size_t)(uint32_t)s_) * 8 + h];                                 \
        ff = *(const ushort4*)((const char*)ft +                                 \
                               (((size_t)(uint32_t)s_) << 9) + lane * 8);        \
      }                                                                          \
    } while (0)

#define PR(ee, ff)                                                               \
    do {                                                                         \
      float v_ = ee + ern;                                                       \
      v_ = fmaxf(v_, NEG_SLOPE * v_);                                            \
      float w_ = __expf(v_);                                                     \
      sw += w_;                                                                  \
      o0 = fmaf(w_, bf2f(ff.x), o0);                                             \
      o1 = fmaf(w_, bf2f(ff.y), o1);                                             \
      o2 = fmaf(w_, bf2f(ff.z), o2);                                             \
      o3 = fmaf(w_, bf2f(ff.w), o3);                                             \
    } while (0)

    LD(beg + 0, e0, f0); LD(beg + 1, e1, f1);
    LD(beg + 2, e2, f2); LD(beg + 3, e3, f3);

    for (int i = beg; i < end; i += 4) {
      PR(e0, f0); LD(i + 4, e0, f0);
      if (i + 1 < end) { PR(e1, f1); LD(i + 5, e1, f1); }
      if (i + 2 < end) { PR(e2, f2); LD(i + 6, e2, f2); }
      if (i + 3 < end) { PR(e3, f3); LD(i + 7, e3, f3); }
    }
#undef LD
#undef PR
    float inv = 1.0f / sw;
    o0 *= inv; o1 *= inv; o2 *= inv; o3 *= inv;
  }
  *(float4*)(&rst[(size_t)n * 256 + lane * 4]) = make_float4(o0, o1, o2, o3);
}

// ---------------------------------------------------------------------------
extern "C" void kernel_launch(void* const* d_in, const int* in_sizes, int n_in,
                              void* d_out, int out_size, void* d_ws, size_t ws_size,
                              hipStream_t stream) {
  const float* master = (const float*)d_in[0];
  const float* af0    = (const float*)d_in[1];
  const float* af1    = (const float*)d_in[2];
  const int*   src0   = (const int*)d_in[3];
  const int*   dst0   = (const int*)d_in[4];
  const int*   src1   = (const int*)d_in[5];
  const int*   dst1   = (const int*)d_in[6];
  const float* Wm     = (const float*)d_in[7];
  const float* W0     = (const float*)d_in[8];
  const float* W1     = (const float*)d_in[9];
  const float* attn_l = (const float*)d_in[10];
  const float* attn_r = (const float*)d_in[11];

  const int Nm  = in_sizes[0] / 128;
  const int Na0 = in_sizes[1] / 128;
  const int Na1 = in_sizes[2] / 128;
  const int E0  = in_sizes[3];
  const int E1  = in_sizes[5];
  float* rst = (float*)d_out;

  char* ws = (char*)d_ws;
  size_t off = 0;
  auto alloc = [&](size_t b) -> char* {
    char* p = ws + off;
    off += (b + 511) & ~(size_t)511;
    return p;
  };
  unsigned short* ft = (unsigned short*)alloc((size_t)(Na0 + Na1) * 256 * sizeof(unsigned short));
  float* el = (float*)alloc((size_t)(Na0 + Na1) * 8 * sizeof(float));
  float* er = (float*)alloc((size_t)Nm * 8 * sizeof(float));
  unsigned short* Wtm = (unsigned short*)alloc(256 * 128 * sizeof(unsigned short));
  unsigned short* Wt0 = (unsigned short*)alloc(256 * 128 * sizeof(unsigned short));
  unsigned short* Wt1 = (unsigned short*)alloc(256 * 128 * sizeof(unsigned short));
  int* deg     = (int*)alloc((size_t)Nm * sizeof(int));
  int* offs    = (int*)alloc((size_t)(Nm + 1) * sizeof(int));
  int* cursor  = (int*)alloc((size_t)Nm * sizeof(int));
  int* partial = (int*)alloc(64 * sizeof(int));
  int* pbase   = (int*)alloc(64 * sizeof(int));
  int* slots   = (int*)alloc((size_t)(E0 + E1) * sizeof(int));

  wt_kernel<<<dim3(128, 3), 256, 0, stream>>>(Wm, W0, W1, Wtm, Wt0, Wt1);

  int Nmax = Nm > Na0 ? Nm : Na0; if (Na1 > Nmax) Nmax = Na1;
  const int mb = (Nmax + 127) / 128;
  proj_mfma_kernel<<<dim3(mb, 2, 3), 256, 0, stream>>>(
      master, af0, af1, Wtm, Wt0, Wt1, attn_l, attn_r,
      Nm, Na0, Na1, ft, el, er);

  hipMemsetAsync(deg, 0, (size_t)Nm * sizeof(int), stream);
  count_deg_kernel<<<1024, 256, 0, stream>>>(dst0, E0, dst1, E1, deg);
  const int nb = (Nm + 1023) / 1024;   // <= 64
  block_reduce_kernel<<<nb, 1024, 0, stream>>>(deg, partial, Nm);
  partial_scan_kernel<<<1, 64, 0, stream>>>(partial, pbase, nb, offs, Nm);
  apply_scan_kernel<<<nb, 1024, 0, stream>>>(deg, pbase, offs, cursor, Nm);
  scatter_kernel<<<1024, 256, 0, stream>>>(src0, dst0, E0, src1, dst1, E1, cursor, slots, Na0);

  aggregate_kernel<<<(Nm + 3) / 4, 256, 0, stream>>>(offs, slots, el, er, ft, rst, Nm);
}

// Round 6
// 256.814 us; speedup vs baseline: 2.0414x; 1.0346x over previous
//
#include <hip/hip_runtime.h>
#include <cstdint>
#include <cstddef>

#define NEG_SLOPE 0.2f

typedef __attribute__((ext_vector_type(8))) short short8;
typedef __attribute__((ext_vector_type(4))) float f32x4;

static __device__ __forceinline__ unsigned short f2bf(float x) {
  uint32_t u = __float_as_uint(x);
  uint32_t r = (u + 0x7FFFu + ((u >> 16) & 1u)) >> 16;
  return (unsigned short)r;
}
static __device__ __forceinline__ float bf2f(unsigned short b) {
  return __uint_as_float(((uint32_t)b) << 16);
}

// ---------------------------------------------------------------------------
// W[128][256] f32 -> Wt[256][128] bf16, x3 weight matrices (blockIdx.y).
// ---------------------------------------------------------------------------
__global__ void wt_kernel(const float* __restrict__ W0, const float* __restrict__ W1,
                          const float* __restrict__ W2,
                          unsigned short* __restrict__ T0, unsigned short* __restrict__ T1,
                          unsigned short* __restrict__ T2) {
  const float* W = (blockIdx.y == 0) ? W0 : (blockIdx.y == 1) ? W1 : W2;
  unsigned short* T = (blockIdx.y == 0) ? T0 : (blockIdx.y == 1) ? T1 : T2;
  int c = blockIdx.x * 2 + (threadIdx.x >> 7);   // 0..255
  int k = threadIdx.x & 127;                     // 0..127
  T[c * 128 + k] = f2bf(W[k * 256 + c]);
}

// ---------------------------------------------------------------------------
// Fused MFMA proj (z selects matrix): ft = bf16(feats) @ bf16(W), el fused.
// Block 256 thr = 4 waves (2x2), row tile 128; BOTH 128-col halves processed
// in-kernel (cbi loop) with feats staged once and A-fragments hoisted to
// registers. As is reused as the bf16 ft-store scratch after the hoist.
// LDS XOR-swizzle byte ^= (row&7)<<4 on all tiles (T2).
// ---------------------------------------------------------------------------
__global__ __launch_bounds__(256)
void proj_mfma_kernel(const float* __restrict__ fm, const float* __restrict__ fa0,
                      const float* __restrict__ fa1,
                      const unsigned short* __restrict__ Wtm,
                      const unsigned short* __restrict__ Wt0,
                      const unsigned short* __restrict__ Wt1,
                      const float* __restrict__ attn_l, const float* __restrict__ attn_r,
                      int Nm, int Na0, int Na1,
                      unsigned short* __restrict__ ft_all, float* __restrict__ el_all,
                      float* __restrict__ er) {
  const int z = blockIdx.z;
  const float* feats = (z == 0) ? fm : (z == 1) ? fa0 : fa1;
  const unsigned short* Wt = (z == 0) ? Wtm : (z == 1) ? Wt0 : Wt1;
  const float* av = (z == 0) ? attn_r : attn_l;
  const int N = (z == 0) ? Nm : (z == 1) ? Na0 : Na1;
  unsigned short* ft_out = (z == 0) ? nullptr
                         : (z == 1) ? ft_all : ft_all + (size_t)Na0 * 256;
  float* el_out = (z == 0) ? er : (z == 1) ? el_all : el_all + (size_t)Na0 * 8;

  const int rb = blockIdx.x * 128;
  if (rb >= N) return;

  __shared__ unsigned short As[128 * 128];   // feats bf16; later: ft scratch
  __shared__ unsigned short Bs[128 * 128];   // Wt half-tile
  const int t = threadIdx.x;

  // stage A once: f32 -> bf16, swizzled
  #pragma unroll
  for (int it = 0; it < 16; ++it) {
    int i = it * 256 + t;
    int r = i >> 5, kc = (i & 31) << 2;
    float4 f = make_float4(0.f, 0.f, 0.f, 0.f);
    if (rb + r < N) f = *(const float4*)(&feats[(size_t)(rb + r) * 128 + kc]);
    ushort4 u;
    u.x = f2bf(f.x); u.y = f2bf(f.y); u.z = f2bf(f.z); u.w = f2bf(f.w);
    uint32_t byte = ((uint32_t)(r * 256 + kc * 2)) ^ ((uint32_t)((r & 7) << 4));
    *(ushort4*)((char*)As + byte) = u;
  }
  __syncthreads();

  const int wid = t >> 6, lane = t & 63;
  const int wm = wid >> 1, wn = wid & 1;
  const int l15 = lane & 15, l4 = lane >> 4;

  // hoist all A-fragments (As is free afterwards)
  short8 af[4][4];
  #pragma unroll
  for (int kb = 0; kb < 4; ++kb)
    #pragma unroll
    for (int mf = 0; mf < 4; ++mf) {
      int row = wm * 64 + mf * 16 + l15;
      uint32_t byte = ((uint32_t)(row * 256 + kb * 64 + l4 * 16)) ^ ((uint32_t)((row & 7) << 4));
      af[kb][mf] = *(const short8*)((const char*)As + byte);
    }

  #pragma unroll
  for (int cbi = 0; cbi < 2; ++cbi) {
    const int cb = cbi * 128;
    __syncthreads();   // prior Bs readers / As-scratch readers done (also drains af reads)
    #pragma unroll
    for (int it = 0; it < 8; ++it) {
      int i = it * 256 + t;
      int c = i >> 4, k8 = (i & 15) << 3;
      short8 w = *(const short8*)(&Wt[(size_t)(cb + c) * 128 + k8]);
      uint32_t byte = ((uint32_t)(c * 256 + k8 * 2)) ^ ((uint32_t)((c & 7) << 4));
      *(short8*)((char*)Bs + byte) = w;
    }
    __syncthreads();

    f32x4 acc[4][4];
    #pragma unroll
    for (int a = 0; a < 4; ++a)
      #pragma unroll
      for (int b = 0; b < 4; ++b)
        acc[a][b] = (f32x4){0.f, 0.f, 0.f, 0.f};

    #pragma unroll
    for (int kb = 0; kb < 4; ++kb) {
      short8 bf[4];
      #pragma unroll
      for (int nf = 0; nf < 4; ++nf) {
        int col = wn * 64 + nf * 16 + l15;
        uint32_t byte = ((uint32_t)(col * 256 + kb * 64 + l4 * 16)) ^ ((uint32_t)((col & 7) << 4));
        bf[nf] = *(const short8*)((const char*)Bs + byte);
      }
      #pragma unroll
      for (int mf = 0; mf < 4; ++mf)
        #pragma unroll
        for (int nf = 0; nf < 4; ++nf)
          acc[mf][nf] = __builtin_amdgcn_mfma_f32_16x16x32_bf16(af[kb][mf], bf[nf], acc[mf][nf], 0, 0, 0);
    }

    // fused el/er dot (2 heads per wave column-half)
    const int head0 = cbi * 4 + wn * 2;
    float avv[4];
    #pragma unroll
    for (int nf = 0; nf < 4; ++nf)
      avv[nf] = av[(head0 + (nf >> 1)) * 32 + (nf & 1) * 16 + l15];

    #pragma unroll
    for (int mf = 0; mf < 4; ++mf) {
      const int rowb = rb + wm * 64 + mf * 16;
      #pragma unroll
      for (int hh = 0; hh < 2; ++hh) {
        float v[4];
        #pragma unroll
        for (int reg = 0; reg < 4; ++reg) {
          float p = fmaf(acc[mf][2 * hh][reg], avv[2 * hh],
                         acc[mf][2 * hh + 1][reg] * avv[2 * hh + 1]);
          p += __shfl_xor(p, 1);
          p += __shfl_xor(p, 2);
          p += __shfl_xor(p, 4);
          p += __shfl_xor(p, 8);
          v[reg] = p;
        }
        if (l15 < 4) {
          int row = rowb + l4 * 4 + l15;
          if (row < N) {
            float val = (l15 == 0) ? v[0] : (l15 == 1) ? v[1] : (l15 == 2) ? v[2] : v[3];
            el_out[(size_t)row * 8 + head0 + hh] = val;
          }
        }
      }
    }

    // ft epilogue via As scratch -> coalesced short8 stores (cols cb..cb+128)
    if (ft_out != nullptr) {
      __syncthreads();
      #pragma unroll
      for (int mf = 0; mf < 4; ++mf)
        #pragma unroll
        for (int nf = 0; nf < 4; ++nf)
          #pragma unroll
          for (int reg = 0; reg < 4; ++reg) {
            int row = wm * 64 + mf * 16 + l4 * 4 + reg;
            int colb = (wn * 64 + nf * 16 + l15) * 2;
            uint32_t byte = ((uint32_t)(row * 256 + colb)) ^ ((uint32_t)((row & 7) << 4));
            *(unsigned short*)((char*)As + byte) = f2bf(acc[mf][nf][reg]);
          }
      __syncthreads();
      #pragma unroll
      for (int it = 0; it < 8; ++it) {
        int i = it * 256 + t;
        int r = i >> 4, j = i & 15;
        int pj = j ^ (r & 7);
        short8 vv = *(const short8*)((const char*)As + r * 256 + pj * 16);
        if (rb + r < N)
          *(short8*)(&ft_out[(size_t)(rb + r) * 256 + cb + j * 8]) = vv;
      }
    }
  }
}

// ---------------------------------------------------------------------------
__global__ void count_deg_kernel(const int* __restrict__ dst0, int E0,
                                 const int* __restrict__ dst1, int E1,
                                 int* __restrict__ deg) {
  int E = E0 + E1;
  for (int i = blockIdx.x * blockDim.x + threadIdx.x; i < E;
       i += gridDim.x * blockDim.x) {
    int d = (i < E0) ? dst0[i] : dst1[i - E0];
    atomicAdd(&deg[d], 1);
  }
}

__global__ __launch_bounds__(1024)
void block_reduce_kernel(const int* __restrict__ deg, int* __restrict__ partial, int n) {
  __shared__ int wsum[16];
  const int t = threadIdx.x;
  int idx = blockIdx.x * 1024 + t;
  int v = (idx < n) ? deg[idx] : 0;
  #pragma unroll
  for (int off = 1; off < 64; off <<= 1) v += __shfl_xor(v, off);
  if ((t & 63) == 0) wsum[t >> 6] = v;
  __syncthreads();
  if (t < 16) {
    int x = wsum[t];
    #pragma unroll
    for (int off = 1; off < 16; off <<= 1) x += __shfl_xor(x, off);
    if (t == 0) partial[blockIdx.x] = x;
  }
}

__global__ __launch_bounds__(64)
void partial_scan_kernel(const int* __restrict__ partial, int* __restrict__ base,
                         int nb, int* __restrict__ offs, int n) {
  const int t = threadIdx.x;
  int v = (t < nb) ? partial[t] : 0;
  int incl = v;
  #pragma unroll
  for (int off = 1; off < 64; off <<= 1) {
    int x = __shfl_up(incl, off);
    if (t >= off) incl += x;
  }
  if (t < nb) base[t] = incl - v;
  if (t == nb - 1) offs[n] = incl;
}

__global__ __launch_bounds__(1024)
void apply_scan_kernel(const int* __restrict__ deg, const int* __restrict__ base,
                       int* __restrict__ offs, int* __restrict__ cursor, int n) {
  __shared__ int wsum[16];
  const int t = threadIdx.x;
  const int idx = blockIdx.x * 1024 + t;
  int v = (idx < n) ? deg[idx] : 0;
  const int lane = t & 63, w = t >> 6;
  int incl = v;
  #pragma unroll
  for (int off = 1; off < 64; off <<= 1) {
    int x = __shfl_up(incl, off);
    if (lane >= off) incl += x;
  }
  if (lane == 63) wsum[w] = incl;
  __syncthreads();
  if (t < 16) {
    int x = wsum[t];
    #pragma unroll
    for (int off = 1; off < 16; off <<= 1) {
      int y = __shfl_up(x, off);
      if (t >= off) x += y;
    }
    wsum[t] = x;
  }
  __syncthreads();
  int excl = base[blockIdx.x] + ((w > 0) ? wsum[w - 1] : 0) + incl - v;
  if (idx < n) {
    offs[idx] = excl;
    cursor[idx] = excl;
  }
}

// ---------------------------------------------------------------------------
// scatter + per-edge softmax weights: w[pos][h] = exp(lrelu(el[src]+er[dst]))
// stored as 8x bf16 (16 B). Moves the exp/lrelu + el/er gathers OUT of the
// latency-critical aggregate loop (single pass, no max-subtraction: lrelu
// logits are O(1)-bounded so exp cannot overflow).
// ---------------------------------------------------------------------------
__global__ void scatter_kernel(const int* __restrict__ src0, const int* __restrict__ dst0, int E0,
                               const int* __restrict__ src1, const int* __restrict__ dst1, int E1,
                               int* __restrict__ cursor, int* __restrict__ slots,
                               uint4* __restrict__ wslots,
                               const float* __restrict__ el, const float* __restrict__ er,
                               int Na0) {
  int E = E0 + E1;
  for (int i = blockIdx.x * blockDim.x + threadIdx.x; i < E;
       i += gridDim.x * blockDim.x) {
    int s, d;
    if (i < E0) { s = src0[i]; d = dst0[i]; }
    else        { s = src1[i - E0] + Na0; d = dst1[i - E0]; }
    int pos = atomicAdd(&cursor[d], 1);
    slots[pos] = s;

    const float* elp = &el[(size_t)s * 8];
    const float* erp = &er[(size_t)d * 8];
    float4 ea = *(const float4*)elp, eb = *(const float4*)(elp + 4);
    float4 ra = *(const float4*)erp, rb = *(const float4*)(erp + 4);
    float w[8];
    w[0] = ea.x + ra.x; w[1] = ea.y + ra.y; w[2] = ea.z + ra.z; w[3] = ea.w + ra.w;
    w[4] = eb.x + rb.x; w[5] = eb.y + rb.y; w[6] = eb.z + rb.z; w[7] = eb.w + rb.w;
    uint4 pk;
    uint32_t* pku = (uint32_t*)&pk;
    #pragma unroll
    for (int q = 0; q < 4; ++q) {
      float v0 = w[2 * q], v1 = w[2 * q + 1];
      v0 = fmaxf(v0, NEG_SLOPE * v0);
      v1 = fmaxf(v1, NEG_SLOPE * v1);
      uint32_t b0 = f2bf(__expf(v0)), b1 = f2bf(__expf(v1));
      pku[q] = b0 | (b1 << 16);
    }
    wslots[pos] = pk;
  }
}

// ---------------------------------------------------------------------------
// one wave per dst node, 8-deep static software pipeline. Dependent chain is
// now ONLY slots[i] -> ft gather (weights are position-indexed, independent).
// lane layout: h = lane>>3, d = (lane&7)*4 + j
// ---------------------------------------------------------------------------
__global__ __launch_bounds__(256)
void aggregate_kernel(const int* __restrict__ offs, const int* __restrict__ slots,
                      const unsigned short* __restrict__ wsl,
                      const unsigned short* __restrict__ ft,
                      float* __restrict__ rst, int Nm) {
  int gid = blockIdx.x * blockDim.x + threadIdx.x;
  int n = gid >> 6;
  int lane = threadIdx.x & 63;
  if (n >= Nm) return;
  int beg = offs[n], end = offs[n + 1];
  int h = lane >> 3;
  float o0 = 0.f, o1 = 0.f, o2 = 0.f, o3 = 0.f;
  if (beg < end) {
    float sw = 0.f;
    float w0 = 0.f, w1 = 0.f, w2 = 0.f, w3 = 0.f, w4 = 0.f, w5 = 0.f, w6 = 0.f, w7 = 0.f;
    ushort4 f0 = {0,0,0,0}, f1 = f0, f2 = f0, f3 = f0, f4 = f0, f5 = f0, f6 = f0, f7 = f0;

#define LD(idx, ww, ff)                                                          \
    do {                                                                         \
      if ((idx) < end) {                                                         \
        ww = bf2f(wsl[(size_t)(uint32_t)(idx) * 8 + h]);                         \
        int s_ = slots[(idx)];                                                   \
        ff = *(const ushort4*)((const char*)ft +                                 \
                               (((size_t)(uint32_t)s_) << 9) + lane * 8);        \
      }                                                                          \
    } while (0)

#define PR(ww, ff)                                                               \
    do {                                                                         \
      sw += ww;                                                                  \
      o0 = fmaf(ww, bf2f(ff.x), o0);                                             \
      o1 = fmaf(ww, bf2f(ff.y), o1);                                             \
      o2 = fmaf(ww, bf2f(ff.z), o2);                                             \
      o3 = fmaf(ww, bf2f(ff.w), o3);                                             \
    } while (0)

    LD(beg + 0, w0, f0); LD(beg + 1, w1, f1); LD(beg + 2, w2, f2); LD(beg + 3, w3, f3);
    LD(beg + 4, w4, f4); LD(beg + 5, w5, f5); LD(beg + 6, w6, f6); LD(beg + 7, w7, f7);

    for (int i = beg; i < end; i += 8) {
      PR(w0, f0); LD(i + 8, w0, f0);
      if (i + 1 < end) { PR(w1, f1); LD(i + 9,  w1, f1); }
      if (i + 2 < end) { PR(w2, f2); LD(i + 10, w2, f2); }
      if (i + 3 < end) { PR(w3, f3); LD(i + 11, w3, f3); }
      if (i + 4 < end) { PR(w4, f4); LD(i + 12, w4, f4); }
      if (i + 5 < end) { PR(w5, f5); LD(i + 13, w5, f5); }
      if (i + 6 < end) { PR(w6, f6); LD(i + 14, w6, f6); }
      if (i + 7 < end) { PR(w7, f7); LD(i + 15, w7, f7); }
    }
#undef LD
#undef PR
    float inv = 1.0f / sw;
    o0 *= inv; o1 *= inv; o2 *= inv; o3 *= inv;
  }
  *(float4*)(&rst[(size_t)n * 256 + lane * 4]) = make_float4(o0, o1, o2, o3);
}

// ---------------------------------------------------------------------------
extern "C" void kernel_launch(void* const* d_in, const int* in_sizes, int n_in,
                              void* d_out, int out_size, void* d_ws, size_t ws_size,
                              hipStream_t stream) {
  const float* master = (const float*)d_in[0];
  const float* af0    = (const float*)d_in[1];
  const float* af1    = (const float*)d_in[2];
  const int*   src0   = (const int*)d_in[3];
  const int*   dst0   = (const int*)d_in[4];
  const int*   src1   = (const int*)d_in[5];
  const int*   dst1   = (const int*)d_in[6];
  const float* Wm     = (const float*)d_in[7];
  const float* W0     = (const float*)d_in[8];
  const float* W1     = (const float*)d_in[9];
  const float* attn_l = (const float*)d_in[10];
  const float* attn_r = (const float*)d_in[11];

  const int Nm  = in_sizes[0] / 128;
  const int Na0 = in_sizes[1] / 128;
  const int Na1 = in_sizes[2] / 128;
  const int E0  = in_sizes[3];
  const int E1  = in_sizes[5];
  float* rst = (float*)d_out;

  char* ws = (char*)d_ws;
  size_t off = 0;
  auto alloc = [&](size_t b) -> char* {
    char* p = ws + off;
    off += (b + 511) & ~(size_t)511;
    return p;
  };
  unsigned short* ft = (unsigned short*)alloc((size_t)(Na0 + Na1) * 256 * sizeof(unsigned short));
  float* el = (float*)alloc((size_t)(Na0 + Na1) * 8 * sizeof(float));
  float* er = (float*)alloc((size_t)Nm * 8 * sizeof(float));
  unsigned short* Wtm = (unsigned short*)alloc(256 * 128 * sizeof(unsigned short));
  unsigned short* Wt0 = (unsigned short*)alloc(256 * 128 * sizeof(unsigned short));
  unsigned short* Wt1 = (unsigned short*)alloc(256 * 128 * sizeof(unsigned short));
  int* deg     = (int*)alloc((size_t)Nm * sizeof(int));
  int* offs    = (int*)alloc((size_t)(Nm + 1) * sizeof(int));
  int* cursor  = (int*)alloc((size_t)Nm * sizeof(int));
  int* partial = (int*)alloc(64 * sizeof(int));
  int* pbase   = (int*)alloc(64 * sizeof(int));
  int* slots   = (int*)alloc((size_t)(E0 + E1) * sizeof(int));
  uint4* wslots = (uint4*)alloc((size_t)(E0 + E1) * sizeof(uint4));

  wt_kernel<<<dim3(128, 3), 256, 0, stream>>>(Wm, W0, W1, Wtm, Wt0, Wt1);

  int Nmax = Nm > Na0 ? Nm : Na0; if (Na1 > Nmax) Nmax = Na1;
  const int mb = (Nmax + 127) / 128;
  proj_mfma_kernel<<<dim3(mb, 1, 3), 256, 0, stream>>>(
      master, af0, af1, Wtm, Wt0, Wt1, attn_l, attn_r,
      Nm, Na0, Na1, ft, el, er);

  hipMemsetAsync(deg, 0, (size_t)Nm * sizeof(int), stream);
  count_deg_kernel<<<1024, 256, 0, stream>>>(dst0, E0, dst1, E1, deg);
  const int nb = (Nm + 1023) / 1024;   // <= 64
  block_reduce_kernel<<<nb, 1024, 0, stream>>>(deg, partial, Nm);
  partial_scan_kernel<<<1, 64, 0, stream>>>(partial, pbase, nb, offs, Nm);
  apply_scan_kernel<<<nb, 1024, 0, stream>>>(deg, pbase, offs, cursor, Nm);
  scatter_kernel<<<1024, 256, 0, stream>>>(src0, dst0, E0, src1, dst1, E1,
                                           cursor, slots, wslots, el, er, Na0);

  aggregate_kernel<<<(Nm + 3) / 4, 256, 0, stream>>>(offs, slots,
                                                     (const unsigned short*)wslots,
                                                     ft, rst, Nm);
}

// Round 7
// 241.830 us; speedup vs baseline: 2.1679x; 1.0620x over previous
//
#include <hip/hip_runtime.h>
#include <cstdint>
#include <cstddef>

#define NEG_SLOPE 0.2f

typedef __attribute__((ext_vector_type(8))) short short8;
typedef __attribute__((ext_vector_type(4))) float f32x4;

static __device__ __forceinline__ unsigned short f2bf(float x) {
  uint32_t u = __float_as_uint(x);
  uint32_t r = (u + 0x7FFFu + ((u >> 16) & 1u)) >> 16;
  return (unsigned short)r;
}
static __device__ __forceinline__ float bf2f(unsigned short b) {
  return __uint_as_float(((uint32_t)b) << 16);
}

// ---------------------------------------------------------------------------
// W[128][256] f32 -> Wt[256][128] bf16, x3 weight matrices (blockIdx.y).
// ---------------------------------------------------------------------------
__global__ void wt_kernel(const float* __restrict__ W0, const float* __restrict__ W1,
                          const float* __restrict__ W2,
                          unsigned short* __restrict__ T0, unsigned short* __restrict__ T1,
                          unsigned short* __restrict__ T2) {
  const float* W = (blockIdx.y == 0) ? W0 : (blockIdx.y == 1) ? W1 : W2;
  unsigned short* T = (blockIdx.y == 0) ? T0 : (blockIdx.y == 1) ? T1 : T2;
  int c = blockIdx.x * 2 + (threadIdx.x >> 7);   // 0..255
  int k = threadIdx.x & 127;                     // 0..127
  T[c * 128 + k] = f2bf(W[k * 256 + c]);
}

// ---------------------------------------------------------------------------
// LDS-free MFMA proj (z selects matrix): ft = bf16(feats) @ bf16(W), el fused.
// Block 256 thr = 4 waves (wm = row-half, wn = col-quarter-pair).
// TRANSPOSED mfma (operands swapped): D[ftcol][node] so lane l15 = node row,
// regs = 4 consecutive ft cols -> direct ushort4 register stores, no LDS,
// no __syncthreads anywhere. A-fragments (feats, f32->bf16 in regs) hoisted
// across both 128-col halves; Wt fragments read straight from L2.
// Fragment maps: 'a' operand row=l15,k=8*l4+j ; 'b' col=l15,same k ;
// D col=l15, row=l4*4+reg (all m89/m91-verified).
// ---------------------------------------------------------------------------
__global__ __launch_bounds__(256)
void proj_mfma_kernel(const float* __restrict__ fm, const float* __restrict__ fa0,
                      const float* __restrict__ fa1,
                      const unsigned short* __restrict__ Wtm,
                      const unsigned short* __restrict__ Wt0,
                      const unsigned short* __restrict__ Wt1,
                      const float* __restrict__ attn_l, const float* __restrict__ attn_r,
                      int Nm, int Na0, int Na1,
                      unsigned short* __restrict__ ft_all, float* __restrict__ el_all,
                      float* __restrict__ er) {
  const int z = blockIdx.z;
  const float* feats = (z == 0) ? fm : (z == 1) ? fa0 : fa1;
  const unsigned short* Wt = (z == 0) ? Wtm : (z == 1) ? Wt0 : Wt1;
  const float* av = (z == 0) ? attn_r : attn_l;
  const int N = (z == 0) ? Nm : (z == 1) ? Na0 : Na1;
  unsigned short* ft_out = (z == 0) ? nullptr
                         : (z == 1) ? ft_all : ft_all + (size_t)Na0 * 256;
  float* el_out = (z == 0) ? er : (z == 1) ? el_all : el_all + (size_t)Na0 * 8;

  const int rb = blockIdx.x * 128;
  if (rb >= N) return;

  const int t = threadIdx.x;
  const int wid = t >> 6, lane = t & 63;
  const int wm = wid >> 1, wn = wid & 1;
  const int l15 = lane & 15, l4 = lane >> 4;

  // ---- load + convert all A fragments (node rows, hoisted across halves)
  const int arow = rb + wm * 64 + l15;     // + mf*16
  short8 af[4][4];                          // [kb][mf]
  #pragma unroll
  for (int mf = 0; mf < 4; ++mf) {
    int row = arow + mf * 16;
    const float* rp = &feats[(size_t)row * 128];
    bool ok = row < N;
    #pragma unroll
    for (int kb = 0; kb < 4; ++kb) {
      float4 lo = make_float4(0.f, 0.f, 0.f, 0.f), hi = lo;
      if (ok) {
        lo = *(const float4*)(rp + kb * 32 + l4 * 8);
        hi = *(const float4*)(rp + kb * 32 + l4 * 8 + 4);
      }
      short8 v;
      v[0] = f2bf(lo.x); v[1] = f2bf(lo.y); v[2] = f2bf(lo.z); v[3] = f2bf(lo.w);
      v[4] = f2bf(hi.x); v[5] = f2bf(hi.y); v[6] = f2bf(hi.z); v[7] = f2bf(hi.w);
      af[kb][mf] = v;
    }
  }

  #pragma unroll
  for (int cbi = 0; cbi < 2; ++cbi) {
    const int cbw = cbi * 128 + wn * 64;
    const int head0 = cbw >> 5;

    // Wt fragments for this wave's 64 cols, straight from global (L2-hot)
    short8 bf[4][4];                        // [kb][nf]
    #pragma unroll
    for (int nf = 0; nf < 4; ++nf) {
      const unsigned short* wp = &Wt[(size_t)(cbw + nf * 16 + l15) * 128];
      #pragma unroll
      for (int kb = 0; kb < 4; ++kb)
        bf[kb][nf] = *(const short8*)(wp + kb * 32 + l4 * 8);
    }

    f32x4 acc[4][4];                        // [mf][nf]
    #pragma unroll
    for (int a = 0; a < 4; ++a)
      #pragma unroll
      for (int b = 0; b < 4; ++b)
        acc[a][b] = (f32x4){0.f, 0.f, 0.f, 0.f};

    #pragma unroll
    for (int kb = 0; kb < 4; ++kb)
      #pragma unroll
      for (int mf = 0; mf < 4; ++mf)
        #pragma unroll
        for (int nf = 0; nf < 4; ++nf)
          // swapped operands: D[ftcol][node]
          acc[mf][nf] = __builtin_amdgcn_mfma_f32_16x16x32_bf16(
              bf[kb][nf], af[kb][mf], acc[mf][nf], 0, 0, 0);

    // av values for this wave's cols: avf[nf][reg]
    float avf[4][4];
    #pragma unroll
    for (int nf = 0; nf < 4; ++nf)
      #pragma unroll
      for (int reg = 0; reg < 4; ++reg)
        avf[nf][reg] = av[(head0 + (nf >> 1)) * 32 + (nf & 1) * 16 + l4 * 4 + reg];

    #pragma unroll
    for (int mf = 0; mf < 4; ++mf) {
      int node = arow + mf * 16;
      bool ok = node < N;
      if (ft_out != nullptr && ok) {
        size_t base = (size_t)node * 256 + cbw + l4 * 4;
        #pragma unroll
        for (int nf = 0; nf < 4; ++nf) {
          ushort4 u;
          u.x = f2bf(acc[mf][nf][0]); u.y = f2bf(acc[mf][nf][1]);
          u.z = f2bf(acc[mf][nf][2]); u.w = f2bf(acc[mf][nf][3]);
          *(ushort4*)(&ft_out[base + nf * 16]) = u;
        }
      }
      #pragma unroll
      for (int hh = 0; hh < 2; ++hh) {
        float p = 0.f;
        #pragma unroll
        for (int reg = 0; reg < 4; ++reg) {
          p = fmaf(acc[mf][2 * hh][reg], avf[2 * hh][reg], p);
          p = fmaf(acc[mf][2 * hh + 1][reg], avf[2 * hh + 1][reg], p);
        }
        p += __shfl_xor(p, 16);
        p += __shfl_xor(p, 32);
        if (ok && l4 == 0)
          el_out[(size_t)node * 8 + head0 + hh] = p;
      }
    }
  }
}

// ---------------------------------------------------------------------------
__global__ void count_deg_kernel(const int* __restrict__ dst0, int E0,
                                 const int* __restrict__ dst1, int E1,
                                 int* __restrict__ deg) {
  int E = E0 + E1;
  for (int i = blockIdx.x * blockDim.x + threadIdx.x; i < E;
       i += gridDim.x * blockDim.x) {
    int d = (i < E0) ? dst0[i] : dst1[i - E0];
    atomicAdd(&deg[d], 1);
  }
}

__global__ __launch_bounds__(1024)
void block_reduce_kernel(const int* __restrict__ deg, int* __restrict__ partial, int n) {
  __shared__ int wsum[16];
  const int t = threadIdx.x;
  int idx = blockIdx.x * 1024 + t;
  int v = (idx < n) ? deg[idx] : 0;
  #pragma unroll
  for (int off = 1; off < 64; off <<= 1) v += __shfl_xor(v, off);
  if ((t & 63) == 0) wsum[t >> 6] = v;
  __syncthreads();
  if (t < 16) {
    int x = wsum[t];
    #pragma unroll
    for (int off = 1; off < 16; off <<= 1) x += __shfl_xor(x, off);
    if (t == 0) partial[blockIdx.x] = x;
  }
}

__global__ __launch_bounds__(64)
void partial_scan_kernel(const int* __restrict__ partial, int* __restrict__ base,
                         int nb, int* __restrict__ offs, int n) {
  const int t = threadIdx.x;
  int v = (t < nb) ? partial[t] : 0;
  int incl = v;
  #pragma unroll
  for (int off = 1; off < 64; off <<= 1) {
    int x = __shfl_up(incl, off);
    if (t >= off) incl += x;
  }
  if (t < nb) base[t] = incl - v;
  if (t == nb - 1) offs[n] = incl;
}

__global__ __launch_bounds__(1024)
void apply_scan_kernel(const int* __restrict__ deg, const int* __restrict__ base,
                       int* __restrict__ offs, int* __restrict__ cursor, int n) {
  __shared__ int wsum[16];
  const int t = threadIdx.x;
  const int idx = blockIdx.x * 1024 + t;
  int v = (idx < n) ? deg[idx] : 0;
  const int lane = t & 63, w = t >> 6;
  int incl = v;
  #pragma unroll
  for (int off = 1; off < 64; off <<= 1) {
    int x = __shfl_up(incl, off);
    if (lane >= off) incl += x;
  }
  if (lane == 63) wsum[w] = incl;
  __syncthreads();
  if (t < 16) {
    int x = wsum[t];
    #pragma unroll
    for (int off = 1; off < 16; off <<= 1) {
      int y = __shfl_up(x, off);
      if (t >= off) x += y;
    }
    wsum[t] = x;
  }
  __syncthreads();
  int excl = base[blockIdx.x] + ((w > 0) ? wsum[w - 1] : 0) + incl - v;
  if (idx < n) {
    offs[idx] = excl;
    cursor[idx] = excl;
  }
}

// ---------------------------------------------------------------------------
// scatter + per-edge softmax weights: w[pos][h] = exp(lrelu(el[src]+er[dst]))
// stored as 8x bf16 (16 B). Single pass softmax (no max-subtraction: lrelu
// logits are O(1)-bounded so exp cannot overflow).
// ---------------------------------------------------------------------------
__global__ void scatter_kernel(const int* __restrict__ src0, const int* __restrict__ dst0, int E0,
                               const int* __restrict__ src1, const int* __restrict__ dst1, int E1,
                               int* __restrict__ cursor, int* __restrict__ slots,
                               uint4* __restrict__ wslots,
                               const float* __restrict__ el, const float* __restrict__ er,
                               int Na0) {
  int E = E0 + E1;
  for (int i = blockIdx.x * blockDim.x + threadIdx.x; i < E;
       i += gridDim.x * blockDim.x) {
    int s, d;
    if (i < E0) { s = src0[i]; d = dst0[i]; }
    else        { s = src1[i - E0] + Na0; d = dst1[i - E0]; }
    int pos = atomicAdd(&cursor[d], 1);
    slots[pos] = s;

    const float* elp = &el[(size_t)s * 8];
    const float* erp = &er[(size_t)d * 8];
    float4 ea = *(const float4*)elp, eb = *(const float4*)(elp + 4);
    float4 ra = *(const float4*)erp, rb = *(const float4*)(erp + 4);
    float w[8];
    w[0] = ea.x + ra.x; w[1] = ea.y + ra.y; w[2] = ea.z + ra.z; w[3] = ea.w + ra.w;
    w[4] = eb.x + rb.x; w[5] = eb.y + rb.y; w[6] = eb.z + rb.z; w[7] = eb.w + rb.w;
    uint4 pk;
    uint32_t* pku = (uint32_t*)&pk;
    #pragma unroll
    for (int q = 0; q < 4; ++q) {
      float v0 = w[2 * q], v1 = w[2 * q + 1];
      v0 = fmaxf(v0, NEG_SLOPE * v0);
      v1 = fmaxf(v1, NEG_SLOPE * v1);
      uint32_t b0 = f2bf(__expf(v0)), b1 = f2bf(__expf(v1));
      pku[q] = b0 | (b1 << 16);
    }
    wslots[pos] = pk;
  }
}

// ---------------------------------------------------------------------------
// one wave per dst node, 8-deep static software pipeline. Dependent chain is
// ONLY slots[i] -> ft gather (weights are position-indexed, independent).
// lane layout: h = lane>>3, d = (lane&7)*4 + j
// ---------------------------------------------------------------------------
__global__ __launch_bounds__(256)
void aggregate_kernel(const int* __restrict__ offs, const int* __restrict__ slots,
                      const unsigned short* __restrict__ wsl,
                      const unsigned short* __restrict__ ft,
                      float* __restrict__ rst, int Nm) {
  int gid = blockIdx.x * blockDim.x + threadIdx.x;
  int n = gid >> 6;
  int lane = threadIdx.x & 63;
  if (n >= Nm) return;
  int beg = offs[n], end = offs[n + 1];
  int h = lane >> 3;
  float o0 = 0.f, o1 = 0.f, o2 = 0.f, o3 = 0.f;
  if (beg < end) {
    float sw = 0.f;
    float w0 = 0.f, w1 = 0.f, w2 = 0.f, w3 = 0.f, w4 = 0.f, w5 = 0.f, w6 = 0.f, w7 = 0.f;
    ushort4 f0 = {0,0,0,0}, f1 = f0, f2 = f0, f3 = f0, f4 = f0, f5 = f0, f6 = f0, f7 = f0;

#define LD(idx, ww, ff)                                                          \
    do {                                                                         \
      if ((idx) < end) {                                                         \
        ww = bf2f(wsl[(size_t)(uint32_t)(idx) * 8 + h]);                         \
        int s_ = slots[(idx)];                                                   \
        ff = *(const ushort4*)((const char*)ft +                                 \
                               (((size_t)(uint32_t)s_) << 9) + lane * 8);        \
      }                                                                          \
    } while (0)

#define PR(ww, ff)                                                               \
    do {                                                                         \
      sw += ww;                                                                  \
      o0 = fmaf(ww, bf2f(ff.x), o0);                                             \
      o1 = fmaf(ww, bf2f(ff.y), o1);                                             \
      o2 = fmaf(ww, bf2f(ff.z), o2);                                             \
      o3 = fmaf(ww, bf2f(ff.w), o3);                                             \
    } while (0)

    LD(beg + 0, w0, f0); LD(beg + 1, w1, f1); LD(beg + 2, w2, f2); LD(beg + 3, w3, f3);
    LD(beg + 4, w4, f4); LD(beg + 5, w5, f5); LD(beg + 6, w6, f6); LD(beg + 7, w7, f7);

    for (int i = beg; i < end; i += 8) {
      PR(w0, f0); LD(i + 8, w0, f0);
      if (i + 1 < end) { PR(w1, f1); LD(i + 9,  w1, f1); }
      if (i + 2 < end) { PR(w2, f2); LD(i + 10, w2, f2); }
      if (i + 3 < end) { PR(w3, f3); LD(i + 11, w3, f3); }
      if (i + 4 < end) { PR(w4, f4); LD(i + 12, w4, f4); }
      if (i + 5 < end) { PR(w5, f5); LD(i + 13, w5, f5); }
      if (i + 6 < end) { PR(w6, f6); LD(i + 14, w6, f6); }
      if (i + 7 < end) { PR(w7, f7); LD(i + 15, w7, f7); }
    }
#undef LD
#undef PR
    float inv = 1.0f / sw;
    o0 *= inv; o1 *= inv; o2 *= inv; o3 *= inv;
  }
  *(float4*)(&rst[(size_t)n * 256 + lane * 4]) = make_float4(o0, o1, o2, o3);
}

// ---------------------------------------------------------------------------
extern "C" void kernel_launch(void* const* d_in, const int* in_sizes, int n_in,
                              void* d_out, int out_size, void* d_ws, size_t ws_size,
                              hipStream_t stream) {
  const float* master = (const float*)d_in[0];
  const float* af0    = (const float*)d_in[1];
  const float* af1    = (const float*)d_in[2];
  const int*   src0   = (const int*)d_in[3];
  const int*   dst0   = (const int*)d_in[4];
  const int*   src1   = (const int*)d_in[5];
  const int*   dst1   = (const int*)d_in[6];
  const float* Wm     = (const float*)d_in[7];
  const float* W0     = (const float*)d_in[8];
  const float* W1     = (const float*)d_in[9];
  const float* attn_l = (const float*)d_in[10];
  const float* attn_r = (const float*)d_in[11];

  const int Nm  = in_sizes[0] / 128;
  const int Na0 = in_sizes[1] / 128;
  const int Na1 = in_sizes[2] / 128;
  const int E0  = in_sizes[3];
  const int E1  = in_sizes[5];
  float* rst = (float*)d_out;

  char* ws = (char*)d_ws;
  size_t off = 0;
  auto alloc = [&](size_t b) -> char* {
    char* p = ws + off;
    off += (b + 511) & ~(size_t)511;
    return p;
  };
  unsigned short* ft = (unsigned short*)alloc((size_t)(Na0 + Na1) * 256 * sizeof(unsigned short));
  float* el = (float*)alloc((size_t)(Na0 + Na1) * 8 * sizeof(float));
  float* er = (float*)alloc((size_t)Nm * 8 * sizeof(float));
  unsigned short* Wtm = (unsigned short*)alloc(256 * 128 * sizeof(unsigned short));
  unsigned short* Wt0 = (unsigned short*)alloc(256 * 128 * sizeof(unsigned short));
  unsigned short* Wt1 = (unsigned short*)alloc(256 * 128 * sizeof(unsigned short));
  int* deg     = (int*)alloc((size_t)Nm * sizeof(int));
  int* offs    = (int*)alloc((size_t)(Nm + 1) * sizeof(int));
  int* cursor  = (int*)alloc((size_t)Nm * sizeof(int));
  int* partial = (int*)alloc(64 * sizeof(int));
  int* pbase   = (int*)alloc(64 * sizeof(int));
  int* slots   = (int*)alloc((size_t)(E0 + E1) * sizeof(int));
  uint4* wslots = (uint4*)alloc((size_t)(E0 + E1) * sizeof(uint4));

  wt_kernel<<<dim3(128, 3), 256, 0, stream>>>(Wm, W0, W1, Wtm, Wt0, Wt1);

  int Nmax = Nm > Na0 ? Nm : Na0; if (Na1 > Nmax) Nmax = Na1;
  const int mb = (Nmax + 127) / 128;
  proj_mfma_kernel<<<dim3(mb, 1, 3), 256, 0, stream>>>(
      master, af0, af1, Wtm, Wt0, Wt1, attn_l, attn_r,
      Nm, Na0, Na1, ft, el, er);

  hipMemsetAsync(deg, 0, (size_t)Nm * sizeof(int), stream);
  count_deg_kernel<<<1024, 256, 0, stream>>>(dst0, E0, dst1, E1, deg);
  const int nb = (Nm + 1023) / 1024;   // <= 64
  block_reduce_kernel<<<nb, 1024, 0, stream>>>(deg, partial, Nm);
  partial_scan_kernel<<<1, 64, 0, stream>>>(partial, pbase, nb, offs, Nm);
  apply_scan_kernel<<<nb, 1024, 0, stream>>>(deg, pbase, offs, cursor, Nm);
  scatter_kernel<<<1024, 256, 0, stream>>>(src0, dst0, E0, src1, dst1, E1,
                                           cursor, slots, wslots, el, er, Na0);

  aggregate_kernel<<<(Nm + 3) / 4, 256, 0, stream>>>(offs, slots,
                                                     (const unsigned short*)wslots,
                                                     ft, rst, Nm);
}

// Round 8
// 230.771 us; speedup vs baseline: 2.2718x; 1.0479x over previous
//
#include <hip/hip_runtime.h>
#include <cstdint>
#include <cstddef>

#define NEG_SLOPE 0.2f

typedef __attribute__((ext_vector_type(8))) short short8;
typedef __attribute__((ext_vector_type(4))) float f32x4;

static __device__ __forceinline__ unsigned short f2bf(float x) {
  uint32_t u = __float_as_uint(x);
  uint32_t r = (u + 0x7FFFu + ((u >> 16) & 1u)) >> 16;
  return (unsigned short)r;
}
static __device__ __forceinline__ float bf2f(unsigned short b) {
  return __uint_as_float(((uint32_t)b) << 16);
}

// ---------------------------------------------------------------------------
// W[128][256] f32 -> Wt[256][128] bf16, x3 weight matrices (blockIdx.y).
// ---------------------------------------------------------------------------
__global__ void wt_kernel(const float* __restrict__ W0, const float* __restrict__ W1,
                          const float* __restrict__ W2,
                          unsigned short* __restrict__ T0, unsigned short* __restrict__ T1,
                          unsigned short* __restrict__ T2) {
  const float* W = (blockIdx.y == 0) ? W0 : (blockIdx.y == 1) ? W1 : W2;
  unsigned short* T = (blockIdx.y == 0) ? T0 : (blockIdx.y == 1) ? T1 : T2;
  int c = blockIdx.x * 2 + (threadIdx.x >> 7);   // 0..255
  int k = threadIdx.x & 127;                     // 0..127
  T[c * 128 + k] = f2bf(W[k * 256 + c]);
}

// ---------------------------------------------------------------------------
// Hybrid MFMA proj (z selects matrix): ft = bf16(feats) @ bf16(W), el fused.
// feats staged in LDS (32 KB bf16, XOR-swizzled, coalesced; ONE barrier);
// A-fragments read from LDS per-kb (low VGPR); Wt fragments hoisted from
// global (L2-hot). Swapped-operand MFMA => D[ftcol][node], lane l15 = node,
// regs = 4 consecutive ft cols -> direct ushort4 register stores.
// ---------------------------------------------------------------------------
__global__ __launch_bounds__(256)
void proj_mfma_kernel(const float* __restrict__ fm, const float* __restrict__ fa0,
                      const float* __restrict__ fa1,
                      const unsigned short* __restrict__ Wtm,
                      const unsigned short* __restrict__ Wt0,
                      const unsigned short* __restrict__ Wt1,
                      const float* __restrict__ attn_l, const float* __restrict__ attn_r,
                      int Nm, int Na0, int Na1,
                      unsigned short* __restrict__ ft_all, float* __restrict__ el_all,
                      float* __restrict__ er) {
  const int z = blockIdx.z;
  const float* feats = (z == 0) ? fm : (z == 1) ? fa0 : fa1;
  const unsigned short* Wt = (z == 0) ? Wtm : (z == 1) ? Wt0 : Wt1;
  const float* av = (z == 0) ? attn_r : attn_l;
  const int N = (z == 0) ? Nm : (z == 1) ? Na0 : Na1;
  unsigned short* ft_out = (z == 0) ? nullptr
                         : (z == 1) ? ft_all : ft_all + (size_t)Na0 * 256;
  float* el_out = (z == 0) ? er : (z == 1) ? el_all : el_all + (size_t)Na0 * 8;

  const int rb = blockIdx.x * 128;
  if (rb >= N) return;

  __shared__ unsigned short As[128 * 128 / 2 * 2];   // 128 rows x 128 cols bf16, 32 KB
  const int t = threadIdx.x;

  // coalesced stage: f32 -> bf16, swizzled (byte ^= (row&7)<<4)
  #pragma unroll
  for (int it = 0; it < 16; ++it) {
    int i = it * 256 + t;
    int r = i >> 5, kc = (i & 31) << 2;
    float4 f = make_float4(0.f, 0.f, 0.f, 0.f);
    if (rb + r < N) f = *(const float4*)(&feats[(size_t)(rb + r) * 128 + kc]);
    ushort4 u;
    u.x = f2bf(f.x); u.y = f2bf(f.y); u.z = f2bf(f.z); u.w = f2bf(f.w);
    uint32_t byte = ((uint32_t)(r * 256 + kc * 2)) ^ ((uint32_t)((r & 7) << 4));
    *(ushort4*)((char*)As + byte) = u;
  }
  __syncthreads();

  const int wid = t >> 6, lane = t & 63;
  const int wm = wid >> 1, wn = wid & 1;
  const int l15 = lane & 15, l4 = lane >> 4;
  const int arow = rb + wm * 64 + l15;     // + mf*16

  #pragma unroll
  for (int cbi = 0; cbi < 2; ++cbi) {
    const int cbw = cbi * 128 + wn * 64;
    const int head0 = cbw >> 5;

    // Wt fragments for this wave's 64 cols, straight from global (L2-hot)
    short8 bf[4][4];                        // [kb][nf]
    #pragma unroll
    for (int nf = 0; nf < 4; ++nf) {
      const unsigned short* wp = &Wt[(size_t)(cbw + nf * 16 + l15) * 128];
      #pragma unroll
      for (int kb = 0; kb < 4; ++kb)
        bf[kb][nf] = *(const short8*)(wp + kb * 32 + l4 * 8);
    }

    f32x4 acc[4][4];                        // [mf][nf]
    #pragma unroll
    for (int a = 0; a < 4; ++a)
      #pragma unroll
      for (int b = 0; b < 4; ++b)
        acc[a][b] = (f32x4){0.f, 0.f, 0.f, 0.f};

    #pragma unroll
    for (int kb = 0; kb < 4; ++kb) {
      short8 af[4];
      #pragma unroll
      for (int mf = 0; mf < 4; ++mf) {
        int row = wm * 64 + mf * 16 + l15;
        uint32_t byte = ((uint32_t)(row * 256 + kb * 64 + l4 * 16)) ^ ((uint32_t)((row & 7) << 4));
        af[mf] = *(const short8*)((const char*)As + byte);
      }
      #pragma unroll
      for (int mf = 0; mf < 4; ++mf)
        #pragma unroll
        for (int nf = 0; nf < 4; ++nf)
          // swapped operands: D[ftcol][node]
          acc[mf][nf] = __builtin_amdgcn_mfma_f32_16x16x32_bf16(
              bf[kb][nf], af[mf], acc[mf][nf], 0, 0, 0);
    }

    float avf[4][4];
    #pragma unroll
    for (int nf = 0; nf < 4; ++nf)
      #pragma unroll
      for (int reg = 0; reg < 4; ++reg)
        avf[nf][reg] = av[(head0 + (nf >> 1)) * 32 + (nf & 1) * 16 + l4 * 4 + reg];

    #pragma unroll
    for (int mf = 0; mf < 4; ++mf) {
      int node = arow + mf * 16;
      bool ok = node < N;
      if (ft_out != nullptr && ok) {
        size_t base = (size_t)node * 256 + cbw + l4 * 4;
        #pragma unroll
        for (int nf = 0; nf < 4; ++nf) {
          ushort4 u;
          u.x = f2bf(acc[mf][nf][0]); u.y = f2bf(acc[mf][nf][1]);
          u.z = f2bf(acc[mf][nf][2]); u.w = f2bf(acc[mf][nf][3]);
          *(ushort4*)(&ft_out[base + nf * 16]) = u;
        }
      }
      #pragma unroll
      for (int hh = 0; hh < 2; ++hh) {
        float p = 0.f;
        #pragma unroll
        for (int reg = 0; reg < 4; ++reg) {
          p = fmaf(acc[mf][2 * hh][reg], avf[2 * hh][reg], p);
          p = fmaf(acc[mf][2 * hh + 1][reg], avf[2 * hh + 1][reg], p);
        }
        p += __shfl_xor(p, 16);
        p += __shfl_xor(p, 32);
        if (ok && l4 == 0)
          el_out[(size_t)node * 8 + head0 + hh] = p;
      }
    }
  }
}

// ---------------------------------------------------------------------------
__global__ void count_deg_kernel(const int* __restrict__ dst0, int E0,
                                 const int* __restrict__ dst1, int E1,
                                 int* __restrict__ deg) {
  int E = E0 + E1;
  for (int i = blockIdx.x * blockDim.x + threadIdx.x; i < E;
       i += gridDim.x * blockDim.x) {
    int d = (i < E0) ? dst0[i] : dst1[i - E0];
    atomicAdd(&deg[d], 1);
  }
}

__global__ __launch_bounds__(1024)
void block_reduce_kernel(const int* __restrict__ deg, int* __restrict__ partial, int n) {
  __shared__ int wsum[16];
  const int t = threadIdx.x;
  int idx = blockIdx.x * 1024 + t;
  int v = (idx < n) ? deg[idx] : 0;
  #pragma unroll
  for (int off = 1; off < 64; off <<= 1) v += __shfl_xor(v, off);
  if ((t & 63) == 0) wsum[t >> 6] = v;
  __syncthreads();
  if (t < 16) {
    int x = wsum[t];
    #pragma unroll
    for (int off = 1; off < 16; off <<= 1) x += __shfl_xor(x, off);
    if (t == 0) partial[blockIdx.x] = x;
  }
}

__global__ __launch_bounds__(64)
void partial_scan_kernel(const int* __restrict__ partial, int* __restrict__ base,
                         int nb, int* __restrict__ offs, int n) {
  const int t = threadIdx.x;
  int v = (t < nb) ? partial[t] : 0;
  int incl = v;
  #pragma unroll
  for (int off = 1; off < 64; off <<= 1) {
    int x = __shfl_up(incl, off);
    if (t >= off) incl += x;
  }
  if (t < nb) base[t] = incl - v;
  if (t == nb - 1) offs[n] = incl;
}

__global__ __launch_bounds__(1024)
void apply_scan_kernel(const int* __restrict__ deg, const int* __restrict__ base,
                       int* __restrict__ offs, int* __restrict__ cursor, int n) {
  __shared__ int wsum[16];
  const int t = threadIdx.x;
  const int idx = blockIdx.x * 1024 + t;
  int v = (idx < n) ? deg[idx] : 0;
  const int lane = t & 63, w = t >> 6;
  int incl = v;
  #pragma unroll
  for (int off = 1; off < 64; off <<= 1) {
    int x = __shfl_up(incl, off);
    if (lane >= off) incl += x;
  }
  if (lane == 63) wsum[w] = incl;
  __syncthreads();
  if (t < 16) {
    int x = wsum[t];
    #pragma unroll
    for (int off = 1; off < 16; off <<= 1) {
      int y = __shfl_up(x, off);
      if (t >= off) x += y;
    }
    wsum[t] = x;
  }
  __syncthreads();
  int excl = base[blockIdx.x] + ((w > 0) ? wsum[w - 1] : 0) + incl - v;
  if (idx < n) {
    offs[idx] = excl;
    cursor[idx] = excl;
  }
}

// ---------------------------------------------------------------------------
// scatter: per edge, ONE 32-byte record {src, w[8] bf16, pad} at the CSR slot
// (single cache line touched per edge on write AND read). Weights are
// exp(lrelu(el[src]+er[dst])) -- single-pass softmax, O(1)-bounded logits.
// ---------------------------------------------------------------------------
__global__ void scatter_kernel(const int* __restrict__ src0, const int* __restrict__ dst0, int E0,
                               const int* __restrict__ src1, const int* __restrict__ dst1, int E1,
                               int* __restrict__ cursor, char* __restrict__ recs,
                               const float* __restrict__ el, const float* __restrict__ er,
                               int Na0) {
  int E = E0 + E1;
  for (int i = blockIdx.x * blockDim.x + threadIdx.x; i < E;
       i += gridDim.x * blockDim.x) {
    int s, d;
    if (i < E0) { s = src0[i]; d = dst0[i]; }
    else        { s = src1[i - E0] + Na0; d = dst1[i - E0]; }
    int pos = atomicAdd(&cursor[d], 1);

    const float* elp = &el[(size_t)s * 8];
    const float* erp = &er[(size_t)d * 8];
    float4 ea = *(const float4*)elp, eb = *(const float4*)(elp + 4);
    float4 ra = *(const float4*)erp, rb = *(const float4*)(erp + 4);
    float w[8];
    w[0] = ea.x + ra.x; w[1] = ea.y + ra.y; w[2] = ea.z + ra.z; w[3] = ea.w + ra.w;
    w[4] = eb.x + rb.x; w[5] = eb.y + rb.y; w[6] = eb.z + rb.z; w[7] = eb.w + rb.w;
    uint32_t pk[4];
    #pragma unroll
    for (int q = 0; q < 4; ++q) {
      float v0 = w[2 * q], v1 = w[2 * q + 1];
      v0 = fmaxf(v0, NEG_SLOPE * v0);
      v1 = fmaxf(v1, NEG_SLOPE * v1);
      uint32_t b0 = f2bf(__expf(v0)), b1 = f2bf(__expf(v1));
      pk[q] = b0 | (b1 << 16);
    }
    char* rp = recs + ((size_t)(uint32_t)pos << 5);
    *(uint4*)rp = make_uint4((uint32_t)s, pk[0], pk[1], pk[2]);
    *(uint4*)(rp + 16) = make_uint4(pk[3], 0u, 0u, 0u);
  }
}

// ---------------------------------------------------------------------------
// one wave per dst node, 8-deep static software pipeline over 32B records.
// Dependent chain: record.src -> ft gather only.
// lane layout: h = lane>>3, d = (lane&7)*4 + j
// ---------------------------------------------------------------------------
__global__ __launch_bounds__(256)
void aggregate_kernel(const int* __restrict__ offs, const char* __restrict__ recs,
                      const unsigned short* __restrict__ ft,
                      float* __restrict__ rst, int Nm) {
  int gid = blockIdx.x * blockDim.x + threadIdx.x;
  int n = gid >> 6;
  int lane = threadIdx.x & 63;
  if (n >= Nm) return;
  int beg = offs[n], end = offs[n + 1];
  int h = lane >> 3;
  const int hoff = 4 + ((h >> 1) << 2);
  float o0 = 0.f, o1 = 0.f, o2 = 0.f, o3 = 0.f;
  if (beg < end) {
    float sw = 0.f;
    float w0 = 0.f, w1 = 0.f, w2 = 0.f, w3 = 0.f, w4 = 0.f, w5 = 0.f, w6 = 0.f, w7 = 0.f;
    ushort4 f0 = {0,0,0,0}, f1 = f0, f2 = f0, f3 = f0, f4 = f0, f5 = f0, f6 = f0, f7 = f0;

#define LD(idx, ww, ff)                                                          \
    do {                                                                         \
      if ((idx) < end) {                                                         \
        const char* rp_ = recs + ((size_t)(uint32_t)(idx) << 5);                 \
        int s_ = *(const int*)rp_;                                               \
        uint32_t wv_ = *(const uint32_t*)(rp_ + hoff);                           \
        ww = __uint_as_float((h & 1) ? (wv_ & 0xffff0000u) : (wv_ << 16));       \
        ff = *(const ushort4*)((const char*)ft +                                 \
                               (((size_t)(uint32_t)s_) << 9) + lane * 8);        \
      }                                                                          \
    } while (0)

#define PR(ww, ff)                                                               \
    do {                                                                         \
      sw += ww;                                                                  \
      o0 = fmaf(ww, bf2f(ff.x), o0);                                             \
      o1 = fmaf(ww, bf2f(ff.y), o1);                                             \
      o2 = fmaf(ww, bf2f(ff.z), o2);                                             \
      o3 = fmaf(ww, bf2f(ff.w), o3);                                             \
    } while (0)

    LD(beg + 0, w0, f0); LD(beg + 1, w1, f1); LD(beg + 2, w2, f2); LD(beg + 3, w3, f3);
    LD(beg + 4, w4, f4); LD(beg + 5, w5, f5); LD(beg + 6, w6, f6); LD(beg + 7, w7, f7);

    for (int i = beg; i < end; i += 8) {
      PR(w0, f0); LD(i + 8, w0, f0);
      if (i + 1 < end) { PR(w1, f1); LD(i + 9,  w1, f1); }
      if (i + 2 < end) { PR(w2, f2); LD(i + 10, w2, f2); }
      if (i + 3 < end) { PR(w3, f3); LD(i + 11, w3, f3); }
      if (i + 4 < end) { PR(w4, f4); LD(i + 12, w4, f4); }
      if (i + 5 < end) { PR(w5, f5); LD(i + 13, w5, f5); }
      if (i + 6 < end) { PR(w6, f6); LD(i + 14, w6, f6); }
      if (i + 7 < end) { PR(w7, f7); LD(i + 15, w7, f7); }
    }
#undef LD
#undef PR
    float inv = 1.0f / sw;
    o0 *= inv; o1 *= inv; o2 *= inv; o3 *= inv;
  }
  *(float4*)(&rst[(size_t)n * 256 + lane * 4]) = make_float4(o0, o1, o2, o3);
}

// ---------------------------------------------------------------------------
extern "C" void kernel_launch(void* const* d_in, const int* in_sizes, int n_in,
                              void* d_out, int out_size, void* d_ws, size_t ws_size,
                              hipStream_t stream) {
  const float* master = (const float*)d_in[0];
  const float* af0    = (const float*)d_in[1];
  const float* af1    = (const float*)d_in[2];
  const int*   src0   = (const int*)d_in[3];
  const int*   dst0   = (const int*)d_in[4];
  const int*   src1   = (const int*)d_in[5];
  const int*   dst1   = (const int*)d_in[6];
  const float* Wm     = (const float*)d_in[7];
  const float* W0     = (const float*)d_in[8];
  const float* W1     = (const float*)d_in[9];
  const float* attn_l = (const float*)d_in[10];
  const float* attn_r = (const float*)d_in[11];

  const int Nm  = in_sizes[0] / 128;
  const int Na0 = in_sizes[1] / 128;
  const int Na1 = in_sizes[2] / 128;
  const int E0  = in_sizes[3];
  const int E1  = in_sizes[5];
  float* rst = (float*)d_out;

  char* ws = (char*)d_ws;
  size_t off = 0;
  auto alloc = [&](size_t b) -> char* {
    char* p = ws + off;
    off += (b + 511) & ~(size_t)511;
    return p;
  };
  unsigned short* ft = (unsigned short*)alloc((size_t)(Na0 + Na1) * 256 * sizeof(unsigned short));
  float* el = (float*)alloc((size_t)(Na0 + Na1) * 8 * sizeof(float));
  float* er = (float*)alloc((size_t)Nm * 8 * sizeof(float));
  unsigned short* Wtm = (unsigned short*)alloc(256 * 128 * sizeof(unsigned short));
  unsigned short* Wt0 = (unsigned short*)alloc(256 * 128 * sizeof(unsigned short));
  unsigned short* Wt1 = (unsigned short*)alloc(256 * 128 * sizeof(unsigned short));
  int* deg     = (int*)alloc((size_t)Nm * sizeof(int));
  int* offs    = (int*)alloc((size_t)(Nm + 1) * sizeof(int));
  int* cursor  = (int*)alloc((size_t)Nm * sizeof(int));
  int* partial = (int*)alloc(64 * sizeof(int));
  int* pbase   = (int*)alloc(64 * sizeof(int));
  char* recs   = alloc((size_t)(E0 + E1) * 32);

  wt_kernel<<<dim3(128, 3), 256, 0, stream>>>(Wm, W0, W1, Wtm, Wt0, Wt1);

  int Nmax = Nm > Na0 ? Nm : Na0; if (Na1 > Nmax) Nmax = Na1;
  const int mb = (Nmax + 127) / 128;
  proj_mfma_kernel<<<dim3(mb, 1, 3), 256, 0, stream>>>(
      master, af0, af1, Wtm, Wt0, Wt1, attn_l, attn_r,
      Nm, Na0, Na1, ft, el, er);

  hipMemsetAsync(deg, 0, (size_t)Nm * sizeof(int), stream);
  count_deg_kernel<<<1024, 256, 0, stream>>>(dst0, E0, dst1, E1, deg);
  const int nb = (Nm + 1023) / 1024;   // <= 64
  block_reduce_kernel<<<nb, 1024, 0, stream>>>(deg, partial, Nm);
  partial_scan_kernel<<<1, 64, 0, stream>>>(partial, pbase, nb, offs, Nm);
  apply_scan_kernel<<<nb, 1024, 0, stream>>>(deg, pbase, offs, cursor, Nm);
  scatter_kernel<<<1024, 256, 0, stream>>>(src0, dst0, E0, src1, dst1, E1,
                                           cursor, recs, el, er, Na0);

  aggregate_kernel<<<(Nm + 3) / 4, 256, 0, stream>>>(offs, recs, ft, rst, Nm);
}

// Round 9
// 213.832 us; speedup vs baseline: 2.4518x; 1.0792x over previous
//
#include <hip/hip_runtime.h>
#include <cstdint>
#include <cstddef>

#define NEG_SLOPE 0.2f

typedef __attribute__((ext_vector_type(8))) short short8;
typedef __attribute__((ext_vector_type(4))) float f32x4;

static __device__ __forceinline__ unsigned short f2bf(float x) {
  uint32_t u = __float_as_uint(x);
  uint32_t r = (u + 0x7FFFu + ((u >> 16) & 1u)) >> 16;
  return (unsigned short)r;
}
static __device__ __forceinline__ float bf2f(unsigned short b) {
  return __uint_as_float(((uint32_t)b) << 16);
}

// ---------------------------------------------------------------------------
// W[128][256] f32 -> Wt[256][128] bf16, x3 weight matrices (blockIdx.y).
// ---------------------------------------------------------------------------
__global__ void wt_kernel(const float* __restrict__ W0, const float* __restrict__ W1,
                          const float* __restrict__ W2,
                          unsigned short* __restrict__ T0, unsigned short* __restrict__ T1,
                          unsigned short* __restrict__ T2) {
  const float* W = (blockIdx.y == 0) ? W0 : (blockIdx.y == 1) ? W1 : W2;
  unsigned short* T = (blockIdx.y == 0) ? T0 : (blockIdx.y == 1) ? T1 : T2;
  int c = blockIdx.x * 2 + (threadIdx.x >> 7);   // 0..255
  int k = threadIdx.x & 127;                     // 0..127
  T[c * 128 + k] = f2bf(W[k * 256 + c]);
}

// ---------------------------------------------------------------------------
// Hybrid MFMA proj (z selects matrix): ft = bf16(feats) @ bf16(W), el fused.
// feats staged in LDS (32 KB bf16, XOR-swizzled, coalesced; ONE barrier);
// A-fragments read from LDS per-kb (low VGPR); Wt fragments hoisted from
// global (L2-hot). Swapped-operand MFMA => D[ftcol][node], lane l15 = node,
// regs = 4 consecutive ft cols -> direct ushort4 register stores.
// ---------------------------------------------------------------------------
__global__ __launch_bounds__(256)
void proj_mfma_kernel(const float* __restrict__ fm, const float* __restrict__ fa0,
                      const float* __restrict__ fa1,
                      const unsigned short* __restrict__ Wtm,
                      const unsigned short* __restrict__ Wt0,
                      const unsigned short* __restrict__ Wt1,
                      const float* __restrict__ attn_l, const float* __restrict__ attn_r,
                      int Nm, int Na0, int Na1,
                      unsigned short* __restrict__ ft_all, float* __restrict__ el_all,
                      float* __restrict__ er) {
  const int z = blockIdx.z;
  const float* feats = (z == 0) ? fm : (z == 1) ? fa0 : fa1;
  const unsigned short* Wt = (z == 0) ? Wtm : (z == 1) ? Wt0 : Wt1;
  const float* av = (z == 0) ? attn_r : attn_l;
  const int N = (z == 0) ? Nm : (z == 1) ? Na0 : Na1;
  unsigned short* ft_out = (z == 0) ? nullptr
                         : (z == 1) ? ft_all : ft_all + (size_t)Na0 * 256;
  float* el_out = (z == 0) ? er : (z == 1) ? el_all : el_all + (size_t)Na0 * 8;

  const int rb = blockIdx.x * 128;
  if (rb >= N) return;

  __shared__ unsigned short As[128 * 128];   // 32 KB
  const int t = threadIdx.x;

  // coalesced stage: f32 -> bf16, swizzled (byte ^= (row&7)<<4)
  #pragma unroll
  for (int it = 0; it < 16; ++it) {
    int i = it * 256 + t;
    int r = i >> 5, kc = (i & 31) << 2;
    float4 f = make_float4(0.f, 0.f, 0.f, 0.f);
    if (rb + r < N) f = *(const float4*)(&feats[(size_t)(rb + r) * 128 + kc]);
    ushort4 u;
    u.x = f2bf(f.x); u.y = f2bf(f.y); u.z = f2bf(f.z); u.w = f2bf(f.w);
    uint32_t byte = ((uint32_t)(r * 256 + kc * 2)) ^ ((uint32_t)((r & 7) << 4));
    *(ushort4*)((char*)As + byte) = u;
  }
  __syncthreads();

  const int wid = t >> 6, lane = t & 63;
  const int wm = wid >> 1, wn = wid & 1;
  const int l15 = lane & 15, l4 = lane >> 4;
  const int arow = rb + wm * 64 + l15;     // + mf*16

  #pragma unroll
  for (int cbi = 0; cbi < 2; ++cbi) {
    const int cbw = cbi * 128 + wn * 64;
    const int head0 = cbw >> 5;

    short8 bf[4][4];                        // [kb][nf]
    #pragma unroll
    for (int nf = 0; nf < 4; ++nf) {
      const unsigned short* wp = &Wt[(size_t)(cbw + nf * 16 + l15) * 128];
      #pragma unroll
      for (int kb = 0; kb < 4; ++kb)
        bf[kb][nf] = *(const short8*)(wp + kb * 32 + l4 * 8);
    }

    f32x4 acc[4][4];                        // [mf][nf]
    #pragma unroll
    for (int a = 0; a < 4; ++a)
      #pragma unroll
      for (int b = 0; b < 4; ++b)
        acc[a][b] = (f32x4){0.f, 0.f, 0.f, 0.f};

    #pragma unroll
    for (int kb = 0; kb < 4; ++kb) {
      short8 af[4];
      #pragma unroll
      for (int mf = 0; mf < 4; ++mf) {
        int row = wm * 64 + mf * 16 + l15;
        uint32_t byte = ((uint32_t)(row * 256 + kb * 64 + l4 * 16)) ^ ((uint32_t)((row & 7) << 4));
        af[mf] = *(const short8*)((const char*)As + byte);
      }
      #pragma unroll
      for (int mf = 0; mf < 4; ++mf)
        #pragma unroll
        for (int nf = 0; nf < 4; ++nf)
          acc[mf][nf] = __builtin_amdgcn_mfma_f32_16x16x32_bf16(
              bf[kb][nf], af[mf], acc[mf][nf], 0, 0, 0);
    }

    float avf[4][4];
    #pragma unroll
    for (int nf = 0; nf < 4; ++nf)
      #pragma unroll
      for (int reg = 0; reg < 4; ++reg)
        avf[nf][reg] = av[(head0 + (nf >> 1)) * 32 + (nf & 1) * 16 + l4 * 4 + reg];

    #pragma unroll
    for (int mf = 0; mf < 4; ++mf) {
      int node = arow + mf * 16;
      bool ok = node < N;
      if (ft_out != nullptr && ok) {
        size_t base = (size_t)node * 256 + cbw + l4 * 4;
        #pragma unroll
        for (int nf = 0; nf < 4; ++nf) {
          ushort4 u;
          u.x = f2bf(acc[mf][nf][0]); u.y = f2bf(acc[mf][nf][1]);
          u.z = f2bf(acc[mf][nf][2]); u.w = f2bf(acc[mf][nf][3]);
          *(ushort4*)(&ft_out[base + nf * 16]) = u;
        }
      }
      #pragma unroll
      for (int hh = 0; hh < 2; ++hh) {
        float p = 0.f;
        #pragma unroll
        for (int reg = 0; reg < 4; ++reg) {
          p = fmaf(acc[mf][2 * hh][reg], avf[2 * hh][reg], p);
          p = fmaf(acc[mf][2 * hh + 1][reg], avf[2 * hh + 1][reg], p);
        }
        p += __shfl_xor(p, 16);
        p += __shfl_xor(p, 32);
        if (ok && l4 == 0)
          el_out[(size_t)node * 8 + head0 + hh] = p;
      }
    }
  }
}

// ---------------------------------------------------------------------------
__global__ void count_deg_kernel(const int* __restrict__ dst0, int E0,
                                 const int* __restrict__ dst1, int E1,
                                 int* __restrict__ deg) {
  int E = E0 + E1;
  for (int i = blockIdx.x * blockDim.x + threadIdx.x; i < E;
       i += gridDim.x * blockDim.x) {
    int d = (i < E0) ? dst0[i] : dst1[i - E0];
    atomicAdd(&deg[d], 1);
  }
}

__global__ __launch_bounds__(1024)
void block_reduce_kernel(const int* __restrict__ deg, int* __restrict__ partial, int n) {
  __shared__ int wsum[16];
  const int t = threadIdx.x;
  int idx = blockIdx.x * 1024 + t;
  int v = (idx < n) ? deg[idx] : 0;
  #pragma unroll
  for (int off = 1; off < 64; off <<= 1) v += __shfl_xor(v, off);
  if ((t & 63) == 0) wsum[t >> 6] = v;
  __syncthreads();
  if (t < 16) {
    int x = wsum[t];
    #pragma unroll
    for (int off = 1; off < 16; off <<= 1) x += __shfl_xor(x, off);
    if (t == 0) partial[blockIdx.x] = x;
  }
}

__global__ __launch_bounds__(64)
void partial_scan_kernel(const int* __restrict__ partial, int* __restrict__ base,
                         int nb, int* __restrict__ offs, int n) {
  const int t = threadIdx.x;
  int v = (t < nb) ? partial[t] : 0;
  int incl = v;
  #pragma unroll
  for (int off = 1; off < 64; off <<= 1) {
    int x = __shfl_up(incl, off);
    if (t >= off) incl += x;
  }
  if (t < nb) base[t] = incl - v;
  if (t == nb - 1) offs[n] = incl;
}

__global__ __launch_bounds__(1024)
void apply_scan_kernel(const int* __restrict__ deg, const int* __restrict__ base,
                       int* __restrict__ offs, int* __restrict__ cursor, int n) {
  __shared__ int wsum[16];
  const int t = threadIdx.x;
  const int idx = blockIdx.x * 1024 + t;
  int v = (idx < n) ? deg[idx] : 0;
  const int lane = t & 63, w = t >> 6;
  int incl = v;
  #pragma unroll
  for (int off = 1; off < 64; off <<= 1) {
    int x = __shfl_up(incl, off);
    if (lane >= off) incl += x;
  }
  if (lane == 63) wsum[w] = incl;
  __syncthreads();
  if (t < 16) {
    int x = wsum[t];
    #pragma unroll
    for (int off = 1; off < 16; off <<= 1) {
      int y = __shfl_up(x, off);
      if (t >= off) x += y;
    }
    wsum[t] = x;
  }
  __syncthreads();
  int excl = base[blockIdx.x] + ((w > 0) ? wsum[w - 1] : 0) + incl - v;
  if (idx < n) {
    offs[idx] = excl;
    cursor[idx] = excl;
  }
}

// ---------------------------------------------------------------------------
// scatter: per edge, one 32-byte-aligned record {src, w[8] bf16} (20 B used)
// at the CSR slot. Weights are exp(lrelu(el[src]+er[dst])) -- single-pass
// softmax, O(1)-bounded logits.
// ---------------------------------------------------------------------------
__global__ void scatter_kernel(const int* __restrict__ src0, const int* __restrict__ dst0, int E0,
                               const int* __restrict__ src1, const int* __restrict__ dst1, int E1,
                               int* __restrict__ cursor, char* __restrict__ recs,
                               const float* __restrict__ el, const float* __restrict__ er,
                               int Na0) {
  int E = E0 + E1;
  for (int i = blockIdx.x * blockDim.x + threadIdx.x; i < E;
       i += gridDim.x * blockDim.x) {
    int s, d;
    if (i < E0) { s = src0[i]; d = dst0[i]; }
    else        { s = src1[i - E0] + Na0; d = dst1[i - E0]; }
    int pos = atomicAdd(&cursor[d], 1);

    const float* elp = &el[(size_t)s * 8];
    const float* erp = &er[(size_t)d * 8];
    float4 ea = *(const float4*)elp, eb = *(const float4*)(elp + 4);
    float4 ra = *(const float4*)erp, rb = *(const float4*)(erp + 4);
    float w[8];
    w[0] = ea.x + ra.x; w[1] = ea.y + ra.y; w[2] = ea.z + ra.z; w[3] = ea.w + ra.w;
    w[4] = eb.x + rb.x; w[5] = eb.y + rb.y; w[6] = eb.z + rb.z; w[7] = eb.w + rb.w;
    uint32_t pk[4];
    #pragma unroll
    for (int q = 0; q < 4; ++q) {
      float v0 = w[2 * q], v1 = w[2 * q + 1];
      v0 = fmaxf(v0, NEG_SLOPE * v0);
      v1 = fmaxf(v1, NEG_SLOPE * v1);
      uint32_t b0 = f2bf(__expf(v0)), b1 = f2bf(__expf(v1));
      pk[q] = b0 | (b1 << 16);
    }
    char* rp = recs + ((size_t)(uint32_t)pos << 5);
    *(uint4*)rp = make_uint4((uint32_t)s, pk[0], pk[1], pk[2]);
    *(uint32_t*)(rp + 16) = pk[3];
  }
}

// ---------------------------------------------------------------------------
// one wave per dst node, chunk-of-16 gather pipeline:
//   phase1: 16 rec loads (sequential lines, broadcast) -> s[], wv[]
//   phase2: 16 independent ft gathers in one burst
//   phase3: branchless FMA accumulation
// Full chunks have no per-edge branches; single tail chunk uses clamp-to-last
// (gathers hit the last valid edge's row -> cache-hit) + w=0 masking.
// lane layout: h = lane>>3, d = (lane&7)*4 + j
// ---------------------------------------------------------------------------
__global__ __launch_bounds__(256)
void aggregate_kernel(const int* __restrict__ offs, const char* __restrict__ recs,
                      const unsigned short* __restrict__ ft,
                      float* __restrict__ rst, int Nm) {
  int gid = blockIdx.x * blockDim.x + threadIdx.x;
  int n = gid >> 6;
  int lane = threadIdx.x & 63;
  if (n >= Nm) return;
  int beg = offs[n], end = offs[n + 1];
  int h = lane >> 3;
  const int hoff = 4 + ((h >> 1) << 2);
  const char* ftl = (const char*)ft + lane * 8;
  float o0 = 0.f, o1 = 0.f, o2 = 0.f, o3 = 0.f;
  float sw = 0.f;
  if (beg < end) {
    const int last = end - 1;
    int base = beg;

    // ---- full chunks: branchless
    for (; base + 16 <= end; base += 16) {
      uint32_t s[16], wv[16];
      #pragma unroll
      for (int e = 0; e < 16; ++e) {
        const char* rp = recs + ((size_t)(uint32_t)(base + e) << 5);
        s[e] = *(const uint32_t*)rp;
        wv[e] = *(const uint32_t*)(rp + hoff);
      }
      ushort4 f[16];
      #pragma unroll
      for (int e = 0; e < 16; ++e)
        f[e] = *(const ushort4*)(ftl + ((size_t)s[e] << 9));
      #pragma unroll
      for (int e = 0; e < 16; ++e) {
        float w = __uint_as_float((h & 1) ? (wv[e] & 0xffff0000u) : (wv[e] << 16));
        sw += w;
        o0 = fmaf(w, bf2f(f[e].x), o0);
        o1 = fmaf(w, bf2f(f[e].y), o1);
        o2 = fmaf(w, bf2f(f[e].z), o2);
        o3 = fmaf(w, bf2f(f[e].w), o3);
      }
    }

    // ---- tail chunk: clamp-to-last + w masking (clamped gathers cache-hit)
    if (base < end) {
      uint32_t s[16], wv[16];
      #pragma unroll
      for (int e = 0; e < 16; ++e) {
        int idx = base + e; idx = idx > last ? last : idx;
        const char* rp = recs + ((size_t)(uint32_t)idx << 5);
        s[e] = *(const uint32_t*)rp;
        wv[e] = *(const uint32_t*)(rp + hoff);
      }
      ushort4 f[16];
      #pragma unroll
      for (int e = 0; e < 16; ++e)
        f[e] = *(const ushort4*)(ftl + ((size_t)s[e] << 9));
      #pragma unroll
      for (int e = 0; e < 16; ++e) {
        float w = __uint_as_float((h & 1) ? (wv[e] & 0xffff0000u) : (wv[e] << 16));
        w = (base + e <= last) ? w : 0.f;
        sw += w;
        o0 = fmaf(w, bf2f(f[e].x), o0);
        o1 = fmaf(w, bf2f(f[e].y), o1);
        o2 = fmaf(w, bf2f(f[e].z), o2);
        o3 = fmaf(w, bf2f(f[e].w), o3);
      }
    }

    float inv = 1.0f / sw;
    o0 *= inv; o1 *= inv; o2 *= inv; o3 *= inv;
  }
  *(float4*)(&rst[(size_t)n * 256 + lane * 4]) = make_float4(o0, o1, o2, o3);
}

// ---------------------------------------------------------------------------
extern "C" void kernel_launch(void* const* d_in, const int* in_sizes, int n_in,
                              void* d_out, int out_size, void* d_ws, size_t ws_size,
                              hipStream_t stream) {
  const float* master = (const float*)d_in[0];
  const float* af0    = (const float*)d_in[1];
  const float* af1    = (const float*)d_in[2];
  const int*   src0   = (const int*)d_in[3];
  const int*   dst0   = (const int*)d_in[4];
  const int*   src1   = (const int*)d_in[5];
  const int*   dst1   = (const int*)d_in[6];
  const float* Wm     = (const float*)d_in[7];
  const float* W0     = (const float*)d_in[8];
  const float* W1     = (const float*)d_in[9];
  const float* attn_l = (const float*)d_in[10];
  const float* attn_r = (const float*)d_in[11];

  const int Nm  = in_sizes[0] / 128;
  const int Na0 = in_sizes[1] / 128;
  const int Na1 = in_sizes[2] / 128;
  const int E0  = in_sizes[3];
  const int E1  = in_sizes[5];
  float* rst = (float*)d_out;

  char* ws = (char*)d_ws;
  size_t off = 0;
  auto alloc = [&](size_t b) -> char* {
    char* p = ws + off;
    off += (b + 511) & ~(size_t)511;
    return p;
  };
  unsigned short* ft = (unsigned short*)alloc((size_t)(Na0 + Na1) * 256 * sizeof(unsigned short));
  float* el = (float*)alloc((size_t)(Na0 + Na1) * 8 * sizeof(float));
  float* er = (float*)alloc((size_t)Nm * 8 * sizeof(float));
  unsigned short* Wtm = (unsigned short*)alloc(256 * 128 * sizeof(unsigned short));
  unsigned short* Wt0 = (unsigned short*)alloc(256 * 128 * sizeof(unsigned short));
  unsigned short* Wt1 = (unsigned short*)alloc(256 * 128 * sizeof(unsigned short));
  int* deg     = (int*)alloc((size_t)Nm * sizeof(int));
  int* offs    = (int*)alloc((size_t)(Nm + 1) * sizeof(int));
  int* cursor  = (int*)alloc((size_t)Nm * sizeof(int));
  int* partial = (int*)alloc(64 * sizeof(int));
  int* pbase   = (int*)alloc(64 * sizeof(int));
  char* recs   = alloc((size_t)(E0 + E1) * 32);

  wt_kernel<<<dim3(128, 3), 256, 0, stream>>>(Wm, W0, W1, Wtm, Wt0, Wt1);

  int Nmax = Nm > Na0 ? Nm : Na0; if (Na1 > Nmax) Nmax = Na1;
  const int mb = (Nmax + 127) / 128;
  proj_mfma_kernel<<<dim3(mb, 1, 3), 256, 0, stream>>>(
      master, af0, af1, Wtm, Wt0, Wt1, attn_l, attn_r,
      Nm, Na0, Na1, ft, el, er);

  hipMemsetAsync(deg, 0, (size_t)Nm * sizeof(int), stream);
  count_deg_kernel<<<1024, 256, 0, stream>>>(dst0, E0, dst1, E1, deg);
  const int nb = (Nm + 1023) / 1024;   // <= 64
  block_reduce_kernel<<<nb, 1024, 0, stream>>>(deg, partial, Nm);
  partial_scan_kernel<<<1, 64, 0, stream>>>(partial, pbase, nb, offs, Nm);
  apply_scan_kernel<<<nb, 1024, 0, stream>>>(deg, pbase, offs, cursor, Nm);
  scatter_kernel<<<1024, 256, 0, stream>>>(src0, dst0, E0, src1, dst1, E1,
                                           cursor, recs, el, er, Na0);

  aggregate_kernel<<<(Nm + 3) / 4, 256, 0, stream>>>(offs, recs, ft, rst, Nm);
}

// Round 10
// 208.712 us; speedup vs baseline: 2.5119x; 1.0245x over previous
//
#include <hip/hip_runtime.h>
#include <cstdint>
#include <cstddef>

#define NEG_SLOPE 0.2f

typedef __attribute__((ext_vector_type(8))) short short8;
typedef __attribute__((ext_vector_type(4))) float f32x4;

static __device__ __forceinline__ unsigned short f2bf(float x) {
  uint32_t u = __float_as_uint(x);
  uint32_t r = (u + 0x7FFFu + ((u >> 16) & 1u)) >> 16;
  return (unsigned short)r;
}
static __device__ __forceinline__ float bf2f(unsigned short b) {
  return __uint_as_float(((uint32_t)b) << 16);
}

// ---------------------------------------------------------------------------
// W[128][256] f32 -> Wt[256][128] bf16, x3 weight matrices (blockIdx.y).
// ---------------------------------------------------------------------------
__global__ void wt_kernel(const float* __restrict__ W0, const float* __restrict__ W1,
                          const float* __restrict__ W2,
                          unsigned short* __restrict__ T0, unsigned short* __restrict__ T1,
                          unsigned short* __restrict__ T2) {
  const float* W = (blockIdx.y == 0) ? W0 : (blockIdx.y == 1) ? W1 : W2;
  unsigned short* T = (blockIdx.y == 0) ? T0 : (blockIdx.y == 1) ? T1 : T2;
  int c = blockIdx.x * 2 + (threadIdx.x >> 7);   // 0..255
  int k = threadIdx.x & 127;                     // 0..127
  T[c * 128 + k] = f2bf(W[k * 256 + c]);
}

// ---------------------------------------------------------------------------
// MFMA proj, occupancy-first shape: row tile 64 (LDS 16 KB), 4 waves each
// owning a DIFFERENT 64-col quarter (all 256 cols in one pass, no col loop).
// Wt fragments prefetched from L2 BEFORE staging so latency overlaps.
// One barrier total. Swapped-operand MFMA => D[ftcol][node]: lane l15 = node,
// regs = 4 consecutive ft cols -> direct ushort4 register stores.
// ---------------------------------------------------------------------------
__global__ __launch_bounds__(256)
void proj_mfma_kernel(const float* __restrict__ fm, const float* __restrict__ fa0,
                      const float* __restrict__ fa1,
                      const unsigned short* __restrict__ Wtm,
                      const unsigned short* __restrict__ Wt0,
                      const unsigned short* __restrict__ Wt1,
                      const float* __restrict__ attn_l, const float* __restrict__ attn_r,
                      int Nm, int Na0, int Na1,
                      unsigned short* __restrict__ ft_all, float* __restrict__ el_all,
                      float* __restrict__ er) {
  const int z = blockIdx.z;
  const float* feats = (z == 0) ? fm : (z == 1) ? fa0 : fa1;
  const unsigned short* Wt = (z == 0) ? Wtm : (z == 1) ? Wt0 : Wt1;
  const float* av = (z == 0) ? attn_r : attn_l;
  const int N = (z == 0) ? Nm : (z == 1) ? Na0 : Na1;
  unsigned short* ft_out = (z == 0) ? nullptr
                         : (z == 1) ? ft_all : ft_all + (size_t)Na0 * 256;
  float* el_out = (z == 0) ? er : (z == 1) ? el_all : el_all + (size_t)Na0 * 8;

  const int rb = blockIdx.x * 64;
  if (rb >= N) return;

  __shared__ unsigned short As[64 * 128];   // 16 KB
  const int t = threadIdx.x;
  const int wid = t >> 6, lane = t & 63;
  const int l15 = lane & 15, l4 = lane >> 4;
  const int cbw = wid * 64;                 // this wave's col quarter
  const int head0 = cbw >> 5;               // 2 heads per wave

  // ---- prefetch Wt fragments (L2-hot, no LDS dependency)
  short8 bf[4][4];                          // [kb][nf]
  #pragma unroll
  for (int nf = 0; nf < 4; ++nf) {
    const unsigned short* wp = &Wt[(size_t)(cbw + nf * 16 + l15) * 128];
    #pragma unroll
    for (int kb = 0; kb < 4; ++kb)
      bf[kb][nf] = *(const short8*)(wp + kb * 32 + l4 * 8);
  }

  // ---- stage feats rows rb..rb+64: f32 -> bf16, swizzled, coalesced
  #pragma unroll
  for (int it = 0; it < 8; ++it) {
    int i = it * 256 + t;                   // 0..2047
    int r = i >> 5, kc = (i & 31) << 2;     // row 0..63, col 0..124
    float4 f = make_float4(0.f, 0.f, 0.f, 0.f);
    if (rb + r < N) f = *(const float4*)(&feats[(size_t)(rb + r) * 128 + kc]);
    ushort4 u;
    u.x = f2bf(f.x); u.y = f2bf(f.y); u.z = f2bf(f.z); u.w = f2bf(f.w);
    uint32_t byte = ((uint32_t)(r * 256 + kc * 2)) ^ ((uint32_t)((r & 7) << 4));
    *(ushort4*)((char*)As + byte) = u;
  }
  __syncthreads();

  f32x4 acc[4][4];                          // [mf][nf]
  #pragma unroll
  for (int a = 0; a < 4; ++a)
    #pragma unroll
    for (int b = 0; b < 4; ++b)
      acc[a][b] = (f32x4){0.f, 0.f, 0.f, 0.f};

  #pragma unroll
  for (int kb = 0; kb < 4; ++kb) {
    short8 af[4];
    #pragma unroll
    for (int mf = 0; mf < 4; ++mf) {
      int row = mf * 16 + l15;
      uint32_t byte = ((uint32_t)(row * 256 + kb * 64 + l4 * 16)) ^ ((uint32_t)((row & 7) << 4));
      af[mf] = *(const short8*)((const char*)As + byte);
    }
    #pragma unroll
    for (int mf = 0; mf < 4; ++mf)
      #pragma unroll
      for (int nf = 0; nf < 4; ++nf)
        acc[mf][nf] = __builtin_amdgcn_mfma_f32_16x16x32_bf16(
            bf[kb][nf], af[mf], acc[mf][nf], 0, 0, 0);
  }

  float avf[4][4];
  #pragma unroll
  for (int nf = 0; nf < 4; ++nf)
    #pragma unroll
    for (int reg = 0; reg < 4; ++reg)
      avf[nf][reg] = av[(head0 + (nf >> 1)) * 32 + (nf & 1) * 16 + l4 * 4 + reg];

  #pragma unroll
  for (int mf = 0; mf < 4; ++mf) {
    int node = rb + mf * 16 + l15;
    bool ok = node < N;
    if (ft_out != nullptr && ok) {
      size_t base = (size_t)node * 256 + cbw + l4 * 4;
      #pragma unroll
      for (int nf = 0; nf < 4; ++nf) {
        ushort4 u;
        u.x = f2bf(acc[mf][nf][0]); u.y = f2bf(acc[mf][nf][1]);
        u.z = f2bf(acc[mf][nf][2]); u.w = f2bf(acc[mf][nf][3]);
        *(ushort4*)(&ft_out[base + nf * 16]) = u;
      }
    }
    #pragma unroll
    for (int hh = 0; hh < 2; ++hh) {
      float p = 0.f;
      #pragma unroll
      for (int reg = 0; reg < 4; ++reg) {
        p = fmaf(acc[mf][2 * hh][reg], avf[2 * hh][reg], p);
        p = fmaf(acc[mf][2 * hh + 1][reg], avf[2 * hh + 1][reg], p);
      }
      p += __shfl_xor(p, 16);
      p += __shfl_xor(p, 32);
      if (ok && l4 == 0)
        el_out[(size_t)node * 8 + head0 + hh] = p;
    }
  }
}

// ---------------------------------------------------------------------------
__global__ void count_deg_kernel(const int* __restrict__ dst0, int E0,
                                 const int* __restrict__ dst1, int E1,
                                 int* __restrict__ deg) {
  int E = E0 + E1;
  for (int i = blockIdx.x * blockDim.x + threadIdx.x; i < E;
       i += gridDim.x * blockDim.x) {
    int d = (i < E0) ? dst0[i] : dst1[i - E0];
    atomicAdd(&deg[d], 1);
  }
}

__global__ __launch_bounds__(1024)
void block_reduce_kernel(const int* __restrict__ deg, int* __restrict__ partial, int n) {
  __shared__ int wsum[16];
  const int t = threadIdx.x;
  int idx = blockIdx.x * 1024 + t;
  int v = (idx < n) ? deg[idx] : 0;
  #pragma unroll
  for (int off = 1; off < 64; off <<= 1) v += __shfl_xor(v, off);
  if ((t & 63) == 0) wsum[t >> 6] = v;
  __syncthreads();
  if (t < 16) {
    int x = wsum[t];
    #pragma unroll
    for (int off = 1; off < 16; off <<= 1) x += __shfl_xor(x, off);
    if (t == 0) partial[blockIdx.x] = x;
  }
}

__global__ __launch_bounds__(64)
void partial_scan_kernel(const int* __restrict__ partial, int* __restrict__ base,
                         int nb, int* __restrict__ offs, int n) {
  const int t = threadIdx.x;
  int v = (t < nb) ? partial[t] : 0;
  int incl = v;
  #pragma unroll
  for (int off = 1; off < 64; off <<= 1) {
    int x = __shfl_up(incl, off);
    if (t >= off) incl += x;
  }
  if (t < nb) base[t] = incl - v;
  if (t == nb - 1) offs[n] = incl;
}

__global__ __launch_bounds__(1024)
void apply_scan_kernel(const int* __restrict__ deg, const int* __restrict__ base,
                       int* __restrict__ offs, int* __restrict__ cursor, int n) {
  __shared__ int wsum[16];
  const int t = threadIdx.x;
  const int idx = blockIdx.x * 1024 + t;
  int v = (idx < n) ? deg[idx] : 0;
  const int lane = t & 63, w = t >> 6;
  int incl = v;
  #pragma unroll
  for (int off = 1; off < 64; off <<= 1) {
    int x = __shfl_up(incl, off);
    if (lane >= off) incl += x;
  }
  if (lane == 63) wsum[w] = incl;
  __syncthreads();
  if (t < 16) {
    int x = wsum[t];
    #pragma unroll
    for (int off = 1; off < 16; off <<= 1) {
      int y = __shfl_up(x, off);
      if (t >= off) x += y;
    }
    wsum[t] = x;
  }
  __syncthreads();
  int excl = base[blockIdx.x] + ((w > 0) ? wsum[w - 1] : 0) + incl - v;
  if (idx < n) {
    offs[idx] = excl;
    cursor[idx] = excl;
  }
}

// ---------------------------------------------------------------------------
// scatter: per edge, one 32-byte-aligned record {src, w[8] bf16} (20 B used)
// at the CSR slot. Weights are exp(lrelu(el[src]+er[dst])) -- single-pass
// softmax, O(1)-bounded logits.
// ---------------------------------------------------------------------------
__global__ void scatter_kernel(const int* __restrict__ src0, const int* __restrict__ dst0, int E0,
                               const int* __restrict__ src1, const int* __restrict__ dst1, int E1,
                               int* __restrict__ cursor, char* __restrict__ recs,
                               const float* __restrict__ el, const float* __restrict__ er,
                               int Na0) {
  int E = E0 + E1;
  for (int i = blockIdx.x * blockDim.x + threadIdx.x; i < E;
       i += gridDim.x * blockDim.x) {
    int s, d;
    if (i < E0) { s = src0[i]; d = dst0[i]; }
    else        { s = src1[i - E0] + Na0; d = dst1[i - E0]; }
    int pos = atomicAdd(&cursor[d], 1);

    const float* elp = &el[(size_t)s * 8];
    const float* erp = &er[(size_t)d * 8];
    float4 ea = *(const float4*)elp, eb = *(const float4*)(elp + 4);
    float4 ra = *(const float4*)erp, rb = *(const float4*)(erp + 4);
    float w[8];
    w[0] = ea.x + ra.x; w[1] = ea.y + ra.y; w[2] = ea.z + ra.z; w[3] = ea.w + ra.w;
    w[4] = eb.x + rb.x; w[5] = eb.y + rb.y; w[6] = eb.z + rb.z; w[7] = eb.w + rb.w;
    uint32_t pk[4];
    #pragma unroll
    for (int q = 0; q < 4; ++q) {
      float v0 = w[2 * q], v1 = w[2 * q + 1];
      v0 = fmaxf(v0, NEG_SLOPE * v0);
      v1 = fmaxf(v1, NEG_SLOPE * v1);
      uint32_t b0 = f2bf(__expf(v0)), b1 = f2bf(__expf(v1));
      pk[q] = b0 | (b1 << 16);
    }
    char* rp = recs + ((size_t)(uint32_t)pos << 5);
    *(uint4*)rp = make_uint4((uint32_t)s, pk[0], pk[1], pk[2]);
    *(uint32_t*)(rp + 16) = pk[3];
  }
}

// ---------------------------------------------------------------------------
// one wave per dst node, chunk-of-16 gather pipeline (branchless full chunks;
// clamp-to-last + w=0 masked tail).
// lane layout: h = lane>>3, d = (lane&7)*4 + j
// ---------------------------------------------------------------------------
__global__ __launch_bounds__(256)
void aggregate_kernel(const int* __restrict__ offs, const char* __restrict__ recs,
                      const unsigned short* __restrict__ ft,
                      float* __restrict__ rst, int Nm) {
  int gid = blockIdx.x * blockDim.x + threadIdx.x;
  int n = gid >> 6;
  int lane = threadIdx.x & 63;
  if (n >= Nm) return;
  int beg = offs[n], end = offs[n + 1];
  int h = lane >> 3;
  const int hoff = 4 + ((h >> 1) << 2);
  const char* ftl = (const char*)ft + lane * 8;
  float o0 = 0.f, o1 = 0.f, o2 = 0.f, o3 = 0.f;
  float sw = 0.f;
  if (beg < end) {
    const int last = end - 1;
    int base = beg;

    for (; base + 16 <= end; base += 16) {
      uint32_t s[16], wv[16];
      #pragma unroll
      for (int e = 0; e < 16; ++e) {
        const char* rp = recs + ((size_t)(uint32_t)(base + e) << 5);
        s[e] = *(const uint32_t*)rp;
        wv[e] = *(const uint32_t*)(rp + hoff);
      }
      ushort4 f[16];
      #pragma unroll
      for (int e = 0; e < 16; ++e)
        f[e] = *(const ushort4*)(ftl + ((size_t)s[e] << 9));
      #pragma unroll
      for (int e = 0; e < 16; ++e) {
        float w = __uint_as_float((h & 1) ? (wv[e] & 0xffff0000u) : (wv[e] << 16));
        sw += w;
        o0 = fmaf(w, bf2f(f[e].x), o0);
        o1 = fmaf(w, bf2f(f[e].y), o1);
        o2 = fmaf(w, bf2f(f[e].z), o2);
        o3 = fmaf(w, bf2f(f[e].w), o3);
      }
    }

    if (base < end) {
      uint32_t s[16], wv[16];
      #pragma unroll
      for (int e = 0; e < 16; ++e) {
        int idx = base + e; idx = idx > last ? last : idx;
        const char* rp = recs + ((size_t)(uint32_t)idx << 5);
        s[e] = *(const uint32_t*)rp;
        wv[e] = *(const uint32_t*)(rp + hoff);
      }
      ushort4 f[16];
      #pragma unroll
      for (int e = 0; e < 16; ++e)
        f[e] = *(const ushort4*)(ftl + ((size_t)s[e] << 9));
      #pragma unroll
      for (int e = 0; e < 16; ++e) {
        float w = __uint_as_float((h & 1) ? (wv[e] & 0xffff0000u) : (wv[e] << 16));
        w = (base + e <= last) ? w : 0.f;
        sw += w;
        o0 = fmaf(w, bf2f(f[e].x), o0);
        o1 = fmaf(w, bf2f(f[e].y), o1);
        o2 = fmaf(w, bf2f(f[e].z), o2);
        o3 = fmaf(w, bf2f(f[e].w), o3);
      }
    }

    float inv = 1.0f / sw;
    o0 *= inv; o1 *= inv; o2 *= inv; o3 *= inv;
  }
  *(float4*)(&rst[(size_t)n * 256 + lane * 4]) = make_float4(o0, o1, o2, o3);
}

// ---------------------------------------------------------------------------
extern "C" void kernel_launch(void* const* d_in, const int* in_sizes, int n_in,
                              void* d_out, int out_size, void* d_ws, size_t ws_size,
                              hipStream_t stream) {
  const float* master = (const float*)d_in[0];
  const float* af0    = (const float*)d_in[1];
  const float* af1    = (const float*)d_in[2];
  const int*   src0   = (const int*)d_in[3];
  const int*   dst0   = (const int*)d_in[4];
  const int*   src1   = (const int*)d_in[5];
  const int*   dst1   = (const int*)d_in[6];
  const float* Wm     = (const float*)d_in[7];
  const float* W0     = (const float*)d_in[8];
  const float* W1     = (const float*)d_in[9];
  const float* attn_l = (const float*)d_in[10];
  const float* attn_r = (const float*)d_in[11];

  const int Nm  = in_sizes[0] / 128;
  const int Na0 = in_sizes[1] / 128;
  const int Na1 = in_sizes[2] / 128;
  const int E0  = in_sizes[3];
  const int E1  = in_sizes[5];
  float* rst = (float*)d_out;

  char* ws = (char*)d_ws;
  size_t off = 0;
  auto alloc = [&](size_t b) -> char* {
    char* p = ws + off;
    off += (b + 511) & ~(size_t)511;
    return p;
  };
  unsigned short* ft = (unsigned short*)alloc((size_t)(Na0 + Na1) * 256 * sizeof(unsigned short));
  float* el = (float*)alloc((size_t)(Na0 + Na1) * 8 * sizeof(float));
  float* er = (float*)alloc((size_t)Nm * 8 * sizeof(float));
  unsigned short* Wtm = (unsigned short*)alloc(256 * 128 * sizeof(unsigned short));
  unsigned short* Wt0 = (unsigned short*)alloc(256 * 128 * sizeof(unsigned short));
  unsigned short* Wt1 = (unsigned short*)alloc(256 * 128 * sizeof(unsigned short));
  int* deg     = (int*)alloc((size_t)Nm * sizeof(int));
  int* offs    = (int*)alloc((size_t)(Nm + 1) * sizeof(int));
  int* cursor  = (int*)alloc((size_t)Nm * sizeof(int));
  int* partial = (int*)alloc(64 * sizeof(int));
  int* pbase   = (int*)alloc(64 * sizeof(int));
  char* recs   = alloc((size_t)(E0 + E1) * 32);

  wt_kernel<<<dim3(128, 3), 256, 0, stream>>>(Wm, W0, W1, Wtm, Wt0, Wt1);

  int Nmax = Nm > Na0 ? Nm : Na0; if (Na1 > Nmax) Nmax = Na1;
  const int mb = (Nmax + 63) / 64;
  proj_mfma_kernel<<<dim3(mb, 1, 3), 256, 0, stream>>>(
      master, af0, af1, Wtm, Wt0, Wt1, attn_l, attn_r,
      Nm, Na0, Na1, ft, el, er);

  hipMemsetAsync(deg, 0, (size_t)Nm * sizeof(int), stream);
  count_deg_kernel<<<1024, 256, 0, stream>>>(dst0, E0, dst1, E1, deg);
  const int nb = (Nm + 1023) / 1024;   // <= 64
  block_reduce_kernel<<<nb, 1024, 0, stream>>>(deg, partial, Nm);
  partial_scan_kernel<<<1, 64, 0, stream>>>(partial, pbase, nb, offs, Nm);
  apply_scan_kernel<<<nb, 1024, 0, stream>>>(deg, pbase, offs, cursor, Nm);
  scatter_kernel<<<1024, 256, 0, stream>>>(src0, dst0, E0, src1, dst1, E1,
                                           cursor, recs, el, er, Na0);

  aggregate_kernel<<<(Nm + 3) / 4, 256, 0, stream>>>(offs, recs, ft, rst, Nm);
}

// Round 11
// 206.820 us; speedup vs baseline: 2.5349x; 1.0092x over previous
//
#include <hip/hip_runtime.h>
#include <cstdint>
#include <cstddef>

#define NEG_SLOPE 0.2f

typedef __attribute__((ext_vector_type(8))) short short8;
typedef __attribute__((ext_vector_type(4))) float f32x4;

static __device__ __forceinline__ unsigned short f2bf(float x) {
  uint32_t u = __float_as_uint(x);
  uint32_t r = (u + 0x7FFFu + ((u >> 16) & 1u)) >> 16;
  return (unsigned short)r;
}
static __device__ __forceinline__ float bf2f(unsigned short b) {
  return __uint_as_float(((uint32_t)b) << 16);
}

// ---------------------------------------------------------------------------
// W[128][256] f32 -> Wt[256][128] bf16, x3 weight matrices (blockIdx.y).
// ---------------------------------------------------------------------------
__global__ void wt_kernel(const float* __restrict__ W0, const float* __restrict__ W1,
                          const float* __restrict__ W2,
                          unsigned short* __restrict__ T0, unsigned short* __restrict__ T1,
                          unsigned short* __restrict__ T2) {
  const float* W = (blockIdx.y == 0) ? W0 : (blockIdx.y == 1) ? W1 : W2;
  unsigned short* T = (blockIdx.y == 0) ? T0 : (blockIdx.y == 1) ? T1 : T2;
  int c = blockIdx.x * 2 + (threadIdx.x >> 7);   // 0..255
  int k = threadIdx.x & 127;                     // 0..127
  T[c * 128 + k] = f2bf(W[k * 256 + c]);
}

// ---------------------------------------------------------------------------
// MFMA proj, occupancy-first shape: row tile 64 (LDS 16 KB), 4 waves each
// owning a DIFFERENT 64-col quarter. Wt fragments prefetched before staging.
// One barrier. Swapped-operand MFMA => D[ftcol][node]: lane l15 = node,
// regs = 4 consecutive ft cols -> direct ushort4 register stores.
// ---------------------------------------------------------------------------
__global__ __launch_bounds__(256)
void proj_mfma_kernel(const float* __restrict__ fm, const float* __restrict__ fa0,
                      const float* __restrict__ fa1,
                      const unsigned short* __restrict__ Wtm,
                      const unsigned short* __restrict__ Wt0,
                      const unsigned short* __restrict__ Wt1,
                      const float* __restrict__ attn_l, const float* __restrict__ attn_r,
                      int Nm, int Na0, int Na1,
                      unsigned short* __restrict__ ft_all, float* __restrict__ el_all,
                      float* __restrict__ er) {
  const int z = blockIdx.z;
  const float* feats = (z == 0) ? fm : (z == 1) ? fa0 : fa1;
  const unsigned short* Wt = (z == 0) ? Wtm : (z == 1) ? Wt0 : Wt1;
  const float* av = (z == 0) ? attn_r : attn_l;
  const int N = (z == 0) ? Nm : (z == 1) ? Na0 : Na1;
  unsigned short* ft_out = (z == 0) ? nullptr
                         : (z == 1) ? ft_all : ft_all + (size_t)Na0 * 256;
  float* el_out = (z == 0) ? er : (z == 1) ? el_all : el_all + (size_t)Na0 * 8;

  const int rb = blockIdx.x * 64;
  if (rb >= N) return;

  __shared__ unsigned short As[64 * 128];   // 16 KB
  const int t = threadIdx.x;
  const int wid = t >> 6, lane = t & 63;
  const int l15 = lane & 15, l4 = lane >> 4;
  const int cbw = wid * 64;                 // this wave's col quarter
  const int head0 = cbw >> 5;               // 2 heads per wave

  // prefetch Wt fragments (L2-hot, no LDS dependency)
  short8 bf[4][4];                          // [kb][nf]
  #pragma unroll
  for (int nf = 0; nf < 4; ++nf) {
    const unsigned short* wp = &Wt[(size_t)(cbw + nf * 16 + l15) * 128];
    #pragma unroll
    for (int kb = 0; kb < 4; ++kb)
      bf[kb][nf] = *(const short8*)(wp + kb * 32 + l4 * 8);
  }

  // stage feats rows rb..rb+64: f32 -> bf16, swizzled, coalesced
  #pragma unroll
  for (int it = 0; it < 8; ++it) {
    int i = it * 256 + t;
    int r = i >> 5, kc = (i & 31) << 2;
    float4 f = make_float4(0.f, 0.f, 0.f, 0.f);
    if (rb + r < N) f = *(const float4*)(&feats[(size_t)(rb + r) * 128 + kc]);
    ushort4 u;
    u.x = f2bf(f.x); u.y = f2bf(f.y); u.z = f2bf(f.z); u.w = f2bf(f.w);
    uint32_t byte = ((uint32_t)(r * 256 + kc * 2)) ^ ((uint32_t)((r & 7) << 4));
    *(ushort4*)((char*)As + byte) = u;
  }
  __syncthreads();

  f32x4 acc[4][4];                          // [mf][nf]
  #pragma unroll
  for (int a = 0; a < 4; ++a)
    #pragma unroll
    for (int b = 0; b < 4; ++b)
      acc[a][b] = (f32x4){0.f, 0.f, 0.f, 0.f};

  #pragma unroll
  for (int kb = 0; kb < 4; ++kb) {
    short8 af[4];
    #pragma unroll
    for (int mf = 0; mf < 4; ++mf) {
      int row = mf * 16 + l15;
      uint32_t byte = ((uint32_t)(row * 256 + kb * 64 + l4 * 16)) ^ ((uint32_t)((row & 7) << 4));
      af[mf] = *(const short8*)((const char*)As + byte);
    }
    #pragma unroll
    for (int mf = 0; mf < 4; ++mf)
      #pragma unroll
      for (int nf = 0; nf < 4; ++nf)
        acc[mf][nf] = __builtin_amdgcn_mfma_f32_16x16x32_bf16(
            bf[kb][nf], af[mf], acc[mf][nf], 0, 0, 0);
  }

  float avf[4][4];
  #pragma unroll
  for (int nf = 0; nf < 4; ++nf)
    #pragma unroll
    for (int reg = 0; reg < 4; ++reg)
      avf[nf][reg] = av[(head0 + (nf >> 1)) * 32 + (nf & 1) * 16 + l4 * 4 + reg];

  #pragma unroll
  for (int mf = 0; mf < 4; ++mf) {
    int node = rb + mf * 16 + l15;
    bool ok = node < N;
    if (ft_out != nullptr && ok) {
      size_t base = (size_t)node * 256 + cbw + l4 * 4;
      #pragma unroll
      for (int nf = 0; nf < 4; ++nf) {
        ushort4 u;
        u.x = f2bf(acc[mf][nf][0]); u.y = f2bf(acc[mf][nf][1]);
        u.z = f2bf(acc[mf][nf][2]); u.w = f2bf(acc[mf][nf][3]);
        *(ushort4*)(&ft_out[base + nf * 16]) = u;
      }
    }
    #pragma unroll
    for (int hh = 0; hh < 2; ++hh) {
      float p = 0.f;
      #pragma unroll
      for (int reg = 0; reg < 4; ++reg) {
        p = fmaf(acc[mf][2 * hh][reg], avf[2 * hh][reg], p);
        p = fmaf(acc[mf][2 * hh + 1][reg], avf[2 * hh + 1][reg], p);
      }
      p += __shfl_xor(p, 16);
      p += __shfl_xor(p, 32);
      if (ok && l4 == 0)
        el_out[(size_t)node * 8 + head0 + hh] = p;
    }
  }
}

// ---------------------------------------------------------------------------
__global__ void count_deg_kernel(const int* __restrict__ dst0, int E0,
                                 const int* __restrict__ dst1, int E1,
                                 int* __restrict__ deg) {
  int E = E0 + E1;
  for (int i = blockIdx.x * blockDim.x + threadIdx.x; i < E;
       i += gridDim.x * blockDim.x) {
    int d = (i < E0) ? dst0[i] : dst1[i - E0];
    atomicAdd(&deg[d], 1);
  }
}

__global__ __launch_bounds__(1024)
void block_reduce_kernel(const int* __restrict__ deg, int* __restrict__ partial, int n) {
  __shared__ int wsum[16];
  const int t = threadIdx.x;
  int idx = blockIdx.x * 1024 + t;
  int v = (idx < n) ? deg[idx] : 0;
  #pragma unroll
  for (int off = 1; off < 64; off <<= 1) v += __shfl_xor(v, off);
  if ((t & 63) == 0) wsum[t >> 6] = v;
  __syncthreads();
  if (t < 16) {
    int x = wsum[t];
    #pragma unroll
    for (int off = 1; off < 16; off <<= 1) x += __shfl_xor(x, off);
    if (t == 0) partial[blockIdx.x] = x;
  }
}

__global__ __launch_bounds__(64)
void partial_scan_kernel(const int* __restrict__ partial, int* __restrict__ base,
                         int nb, int* __restrict__ offs, int n) {
  const int t = threadIdx.x;
  int v = (t < nb) ? partial[t] : 0;
  int incl = v;
  #pragma unroll
  for (int off = 1; off < 64; off <<= 1) {
    int x = __shfl_up(incl, off);
    if (t >= off) incl += x;
  }
  if (t < nb) base[t] = incl - v;
  if (t == nb - 1) offs[n] = incl;
}

__global__ __launch_bounds__(1024)
void apply_scan_kernel(const int* __restrict__ deg, const int* __restrict__ base,
                       int* __restrict__ offs, int* __restrict__ cursor, int n) {
  __shared__ int wsum[16];
  const int t = threadIdx.x;
  const int idx = blockIdx.x * 1024 + t;
  int v = (idx < n) ? deg[idx] : 0;
  const int lane = t & 63, w = t >> 6;
  int incl = v;
  #pragma unroll
  for (int off = 1; off < 64; off <<= 1) {
    int x = __shfl_up(incl, off);
    if (lane >= off) incl += x;
  }
  if (lane == 63) wsum[w] = incl;
  __syncthreads();
  if (t < 16) {
    int x = wsum[t];
    #pragma unroll
    for (int off = 1; off < 16; off <<= 1) {
      int y = __shfl_up(x, off);
      if (t >= off) x += y;
    }
    wsum[t] = x;
  }
  __syncthreads();
  int excl = base[blockIdx.x] + ((w > 0) ? wsum[w - 1] : 0) + incl - v;
  if (idx < n) {
    offs[idx] = excl;
    cursor[idx] = excl;
  }
}

// ---------------------------------------------------------------------------
// scatter: per edge, one 32-byte-aligned record {src, w[8] bf16} (20 B used)
// at the CSR slot. Weights are exp(lrelu(el[src]+er[dst])) -- single-pass
// softmax, O(1)-bounded logits.
// ---------------------------------------------------------------------------
__global__ void scatter_kernel(const int* __restrict__ src0, const int* __restrict__ dst0, int E0,
                               const int* __restrict__ src1, const int* __restrict__ dst1, int E1,
                               int* __restrict__ cursor, char* __restrict__ recs,
                               const float* __restrict__ el, const float* __restrict__ er,
                               int Na0) {
  int E = E0 + E1;
  for (int i = blockIdx.x * blockDim.x + threadIdx.x; i < E;
       i += gridDim.x * blockDim.x) {
    int s, d;
    if (i < E0) { s = src0[i]; d = dst0[i]; }
    else        { s = src1[i - E0] + Na0; d = dst1[i - E0]; }
    int pos = atomicAdd(&cursor[d], 1);

    const float* elp = &el[(size_t)s * 8];
    const float* erp = &er[(size_t)d * 8];
    float4 ea = *(const float4*)elp, eb = *(const float4*)(elp + 4);
    float4 ra = *(const float4*)erp, rb = *(const float4*)(erp + 4);
    float w[8];
    w[0] = ea.x + ra.x; w[1] = ea.y + ra.y; w[2] = ea.z + ra.z; w[3] = ea.w + ra.w;
    w[4] = eb.x + rb.x; w[5] = eb.y + rb.y; w[6] = eb.z + rb.z; w[7] = eb.w + rb.w;
    uint32_t pk[4];
    #pragma unroll
    for (int q = 0; q < 4; ++q) {
      float v0 = w[2 * q], v1 = w[2 * q + 1];
      v0 = fmaxf(v0, NEG_SLOPE * v0);
      v1 = fmaxf(v1, NEG_SLOPE * v1);
      uint32_t b0 = f2bf(__expf(v0)), b1 = f2bf(__expf(v1));
      pk[q] = b0 | (b1 << 16);
    }
    char* rp = recs + ((size_t)(uint32_t)pos << 5);
    *(uint4*)rp = make_uint4((uint32_t)s, pk[0], pk[1], pk[2]);
    *(uint32_t*)(rp + 16) = pk[3];
  }
}

// ---------------------------------------------------------------------------
// one wave per dst node. Records are wave-uniform -> readfirstlane forces the
// record/offs loads onto the SCALAR path (s_load, no VMEM, no VGPR addressing)
// and the src index into an SGPR, so the ft gather is saddr + loop-invariant
// lane offset (zero per-edge VALU addressing). Weight picked from 4 SGPRs by
// 3 cndmask (loop-invariant masks) + shift.
// lane layout: h = lane>>3, d = (lane&7)*4 + j
// ---------------------------------------------------------------------------
__global__ __launch_bounds__(256)
void aggregate_kernel(const int* __restrict__ offs, const char* __restrict__ recs,
                      const unsigned short* __restrict__ ft,
                      float* __restrict__ rst, int Nm) {
  int gid = blockIdx.x * blockDim.x + threadIdx.x;
  int n = gid >> 6;
  int lane = threadIdx.x & 63;
  if (n >= Nm) return;
  const int nu = __builtin_amdgcn_readfirstlane(n);   // wave-uniform node id
  const int beg = offs[nu], end = offs[nu + 1];       // scalar loads
  const int h = lane >> 3;
  const char* ftl = (const char*)ft + lane * 8;
  float o0 = 0.f, o1 = 0.f, o2 = 0.f, o3 = 0.f;
  float sw = 0.f;

  #pragma unroll 4
  for (int i = beg; i < end; ++i) {
    const uint32_t* rp = (const uint32_t*)(recs + ((size_t)(uint32_t)i << 5));
    uint32_t sct = rp[0];                         // SGPR: src index
    uint32_t d0 = rp[1], d1 = rp[2], d2 = rp[3], d3 = rp[4];   // SGPR: weights
    uint2 g = *(const uint2*)(ftl + ((size_t)sct << 9));        // the only gather
    uint32_t wa = (h & 2) ? d1 : d0;
    uint32_t wb = (h & 2) ? d3 : d2;
    uint32_t wsl = (h & 4) ? wb : wa;
    float w = __uint_as_float((h & 1) ? (wsl & 0xffff0000u) : (wsl << 16));
    sw += w;
    o0 = fmaf(w, __uint_as_float(g.x << 16), o0);
    o1 = fmaf(w, __uint_as_float(g.x & 0xffff0000u), o1);
    o2 = fmaf(w, __uint_as_float(g.y << 16), o2);
    o3 = fmaf(w, __uint_as_float(g.y & 0xffff0000u), o3);
  }

  if (beg < end) {
    float inv = 1.0f / sw;
    o0 *= inv; o1 *= inv; o2 *= inv; o3 *= inv;
  }
  *(float4*)(&rst[(size_t)n * 256 + lane * 4]) = make_float4(o0, o1, o2, o3);
}

// ---------------------------------------------------------------------------
extern "C" void kernel_launch(void* const* d_in, const int* in_sizes, int n_in,
                              void* d_out, int out_size, void* d_ws, size_t ws_size,
                              hipStream_t stream) {
  const float* master = (const float*)d_in[0];
  const float* af0    = (const float*)d_in[1];
  const float* af1    = (const float*)d_in[2];
  const int*   src0   = (const int*)d_in[3];
  const int*   dst0   = (const int*)d_in[4];
  const int*   src1   = (const int*)d_in[5];
  const int*   dst1   = (const int*)d_in[6];
  const float* Wm     = (const float*)d_in[7];
  const float* W0     = (const float*)d_in[8];
  const float* W1     = (const float*)d_in[9];
  const float* attn_l = (const float*)d_in[10];
  const float* attn_r = (const float*)d_in[11];

  const int Nm  = in_sizes[0] / 128;
  const int Na0 = in_sizes[1] / 128;
  const int Na1 = in_sizes[2] / 128;
  const int E0  = in_sizes[3];
  const int E1  = in_sizes[5];
  float* rst = (float*)d_out;

  char* ws = (char*)d_ws;
  size_t off = 0;
  auto alloc = [&](size_t b) -> char* {
    char* p = ws + off;
    off += (b + 511) & ~(size_t)511;
    return p;
  };
  unsigned short* ft = (unsigned short*)alloc((size_t)(Na0 + Na1) * 256 * sizeof(unsigned short));
  float* el = (float*)alloc((size_t)(Na0 + Na1) * 8 * sizeof(float));
  float* er = (float*)alloc((size_t)Nm * 8 * sizeof(float));
  unsigned short* Wtm = (unsigned short*)alloc(256 * 128 * sizeof(unsigned short));
  unsigned short* Wt0 = (unsigned short*)alloc(256 * 128 * sizeof(unsigned short));
  unsigned short* Wt1 = (unsigned short*)alloc(256 * 128 * sizeof(unsigned short));
  int* deg     = (int*)alloc((size_t)Nm * sizeof(int));
  int* offs    = (int*)alloc((size_t)(Nm + 1) * sizeof(int));
  int* cursor  = (int*)alloc((size_t)Nm * sizeof(int));
  int* partial = (int*)alloc(64 * sizeof(int));
  int* pbase   = (int*)alloc(64 * sizeof(int));
  char* recs   = alloc((size_t)(E0 + E1) * 32);

  wt_kernel<<<dim3(128, 3), 256, 0, stream>>>(Wm, W0, W1, Wtm, Wt0, Wt1);

  int Nmax = Nm > Na0 ? Nm : Na0; if (Na1 > Nmax) Nmax = Na1;
  const int mb = (Nmax + 63) / 64;
  proj_mfma_kernel<<<dim3(mb, 1, 3), 256, 0, stream>>>(
      master, af0, af1, Wtm, Wt0, Wt1, attn_l, attn_r,
      Nm, Na0, Na1, ft, el, er);

  hipMemsetAsync(deg, 0, (size_t)Nm * sizeof(int), stream);
  count_deg_kernel<<<1024, 256, 0, stream>>>(dst0, E0, dst1, E1, deg);
  const int nb = (Nm + 1023) / 1024;   // <= 64
  block_reduce_kernel<<<nb, 1024, 0, stream>>>(deg, partial, Nm);
  partial_scan_kernel<<<1, 64, 0, stream>>>(partial, pbase, nb, offs, Nm);
  apply_scan_kernel<<<nb, 1024, 0, stream>>>(deg, pbase, offs, cursor, Nm);
  scatter_kernel<<<1024, 256, 0, stream>>>(src0, dst0, E0, src1, dst1, E1,
                                           cursor, recs, el, er, Na0);

  aggregate_kernel<<<(Nm + 3) / 4, 256, 0, stream>>>(offs, recs, ft, rst, Nm);
}